// Round 11
// baseline (436.730 us; speedup 1.0000x reference)
//
#include <hip/hip_runtime.h>
#include <hip/hip_bf16.h>
#include <cstdint>

// SimVQ forward: b=8, n=1024 (R=8192 rows), dim=512, codes C=4096.
// Outputs flat f32: rotated [8192*512], indices-as-float [8192], loss [1].
//
// Round-11: r10 (PASSING) with the score kernel re-tiled BK 64->32:
//   LDS 128->64 KiB => 2 blocks/CU (one scheduling round; the ~28 us
//   K-independent per-block cost overlaps across blocks). 16 K-tiles of 32,
//   2 phases each; stages issue post-barrier AFTER all reads of the target
//   buffer are drained (every wave: reads -> lgkm0 -> MFMA -> barrier).
//   vmcnt(4) per tile keeps the (kt+2) pair in flight. Per-acc MFMA order
//   is bit-identical to r10 => identical scores/flags/partials.
// Margins, cb f32 GEMM, rowsumsq, combine/refine/rotate: r10 bits.

#define R_ROWS 8192
#define DIM    512
#define NCODES 4096
#define BK     16
#define MARGIN      1.5e-2f
#define TILE_MARGIN 1.8e-2f

typedef __attribute__((ext_vector_type(8))) _Float16 f16x8;
typedef __attribute__((ext_vector_type(4))) float f32x4;
typedef __attribute__((ext_vector_type(8))) unsigned short ushort8;

__device__ __forceinline__ void gload_lds16(const void* g, void* l) {
    __builtin_amdgcn_global_load_lds(
        (const __attribute__((address_space(1))) void*)g,
        (__attribute__((address_space(3))) void*)l, 16, 0, 0);
}

// ---------------- generic f32 NT GEMM (cb + fallback) -----------------------
template<int BM, int BN, int TM, int TN, bool ARGMIN>
__launch_bounds__(256)
__global__ void gemm_nt(const float* __restrict__ A, const float* __restrict__ Bm,
                        float* __restrict__ Cout,
                        const float* __restrict__ rowAdd, const float* __restrict__ colAdd,
                        float* __restrict__ pVal, int* __restrict__ pIdx,
                        int M, int N, int K) {
    constexpr int THREADS = (BM / TM) * (BN / TN);
    constexpr int PAD = 4;
    __shared__ float As[BK][BM + PAD];
    __shared__ float Bs[BK][BN + PAD];

    const int tid = threadIdx.x;
    const int tx = tid % (BN / TN);
    const int ty = tid / (BN / TN);
    const int rowBase = blockIdx.y * BM;
    const int colBase = blockIdx.x * BN;

    float acc[TM][TN];
#pragma unroll
    for (int i = 0; i < TM; i++)
#pragma unroll
        for (int j = 0; j < TN; j++) acc[i][j] = 0.f;

    constexpr int A_F4 = BM * BK / 4;
    constexpr int B_F4 = BN * BK / 4;
    const int nK = K / BK;

    for (int kt = 0; kt < nK; ++kt) {
        const int k0 = kt * BK;
#pragma unroll
        for (int f = 0; f < A_F4 / THREADS; ++f) {
            int e = tid + f * THREADS;
            int row = e >> 2;
            int kq = e & 3;
            float4 v = *reinterpret_cast<const float4*>(
                &A[(size_t)(rowBase + row) * K + k0 + kq * 4]);
            As[kq * 4 + 0][row] = v.x; As[kq * 4 + 1][row] = v.y;
            As[kq * 4 + 2][row] = v.z; As[kq * 4 + 3][row] = v.w;
        }
#pragma unroll
        for (int f = 0; f < B_F4 / THREADS; ++f) {
            int e = tid + f * THREADS;
            int row = e >> 2;
            int kq = e & 3;
            float4 v = *reinterpret_cast<const float4*>(
                &Bm[(size_t)(colBase + row) * K + k0 + kq * 4]);
            Bs[kq * 4 + 0][row] = v.x; Bs[kq * 4 + 1][row] = v.y;
            Bs[kq * 4 + 2][row] = v.z; Bs[kq * 4 + 3][row] = v.w;
        }
        __syncthreads();

#pragma unroll
        for (int k = 0; k < BK; k++) {
            float a[TM], b[TN];
#pragma unroll
            for (int i4 = 0; i4 < TM / 4; i4++) {
                float4 v = *reinterpret_cast<const float4*>(&As[k][ty * TM + i4 * 4]);
                a[i4 * 4 + 0] = v.x; a[i4 * 4 + 1] = v.y;
                a[i4 * 4 + 2] = v.z; a[i4 * 4 + 3] = v.w;
            }
#pragma unroll
            for (int j4 = 0; j4 < TN / 4; j4++) {
                float4 v = *reinterpret_cast<const float4*>(&Bs[k][tx * TN + j4 * 4]);
                b[j4 * 4 + 0] = v.x; b[j4 * 4 + 1] = v.y;
                b[j4 * 4 + 2] = v.z; b[j4 * 4 + 3] = v.w;
            }
#pragma unroll
            for (int i = 0; i < TM; i++)
#pragma unroll
                for (int j = 0; j < TN; j++) acc[i][j] = fmaf(a[i], b[j], acc[i][j]);
        }
        __syncthreads();
    }

    if constexpr (!ARGMIN) {
#pragma unroll
        for (int i = 0; i < TM; i++) {
#pragma unroll
            for (int j4 = 0; j4 < TN / 4; j4++) {
                float4 v = make_float4(acc[i][j4 * 4 + 0], acc[i][j4 * 4 + 1],
                                       acc[i][j4 * 4 + 2], acc[i][j4 * 4 + 3]);
                *reinterpret_cast<float4*>(
                    &Cout[(size_t)(rowBase + ty * TM + i) * N + colBase + tx * TN + j4 * 4]) = v;
            }
        }
    } else {
        constexpr int TX = BN / TN;
        __shared__ float rV[BM][TX + 1];
        __shared__ int   rI[BM][TX + 1];
        float xn[TM];
#pragma unroll
        for (int i = 0; i < TM; i++) xn[i] = rowAdd[rowBase + ty * TM + i];
        float cn[TN];
#pragma unroll
        for (int j = 0; j < TN; j++) cn[j] = colAdd[colBase + tx * TN + j];

#pragma unroll
        for (int i = 0; i < TM; i++) {
            float bv = 3.402823466e38f; int bi = 0;
#pragma unroll
            for (int j = 0; j < TN; j++) {
                float s = xn[i] + cn[j] - 2.f * acc[i][j];
                if (s < bv) { bv = s; bi = colBase + tx * TN + j; }
            }
            rV[ty * TM + i][tx] = bv;
            rI[ty * TM + i][tx] = bi;
        }
        __syncthreads();
        if (tid < BM) {
            float bv = 3.402823466e38f; int bi = 0;
#pragma unroll
            for (int t = 0; t < TX; t++) {
                float v = rV[tid][t];
                if (v < bv) { bv = v; bi = rI[tid][t]; }
            }
            int gr = rowBase + tid;
            pVal[(size_t)gr * gridDim.x + blockIdx.x] = bv;
            pIdx[(size_t)gr * gridDim.x + blockIdx.x] = bi;
        }
    }
}

// ------------- per-row sum of squares (r6 bits) -----------------------------
__global__ void rowsumsq(const float* __restrict__ src, float* __restrict__ dst, int nRows) {
    int gw = (blockIdx.x * blockDim.x + threadIdx.x) >> 6;
    int lane = threadIdx.x & 63;
    if (gw >= nRows) return;
    const float4* s4 = reinterpret_cast<const float4*>(src + (size_t)gw * DIM);
    float4 a = s4[lane];
    float4 b = s4[lane + 64];
    float s = a.x * a.x + a.y * a.y + a.z * a.z + a.w * a.w
            + b.x * b.x + b.y * b.y + b.z * b.z + b.w * b.w;
#pragma unroll
    for (int o = 32; o; o >>= 1) s += __shfl_xor(s, o);
    if (lane == 0) dst[gw] = s;
}

// ------------- f32 -> f16 cast (8 elems / thread) ---------------------------
__global__ void cast_f16(const float* __restrict__ src, ushort* __restrict__ dst, int n8) {
    int t = blockIdx.x * blockDim.x + threadIdx.x;
    if (t >= n8) return;
    float4 a = reinterpret_cast<const float4*>(src)[(size_t)t * 2];
    float4 b = reinterpret_cast<const float4*>(src)[(size_t)t * 2 + 1];
    float v[8] = {a.x, a.y, a.z, a.w, b.x, b.y, b.z, b.w};
    ushort8 h;
#pragma unroll
    for (int e = 0; e < 8; ++e) {
        _Float16 hv = (_Float16)v[e];
        h[e] = *reinterpret_cast<unsigned short*>(&hv);
    }
    reinterpret_cast<ushort8*>(dst)[t] = h;
}

// ================= 256x256 MFMA f16 score GEMM, BK=32, 64KB LDS ==============
// [8192 x 512]f16 * [4096 x 512]f16^T. 16 K-tiles of 32. 8 waves (2M x 4N).
// LDS 64 KiB: 2 buf x (A,B) x 16 KB; each half = [256 rows][32 elems], 64B
// rows, g-XOR bank swizzle (r5-verified). 2 phases/tile; stages for (kt+2)
// issue AFTER the post-MFMA barrier (all reads of target buffer provably
// complete: each wave drains lgkm before MFMA before barrier). vmcnt(4) per
// tile => (kt+1) pair landed, (kt+2) pair in flight.

#define NKT 16
#define LDSOFF2(BUF, ISB) ((BUF) * 32768 + (ISB) * 16384)

__device__ __forceinline__ f16x8 read_frag(const char* half_base, int row, int g) {
    int gp = g ^ ((row >> 1) & 3);
    return *reinterpret_cast<const f16x8*>(half_base + row * 64 + gp * 16);
}

__device__ __forceinline__ void stage_half(const ushort* __restrict__ src, int rowBase,
                                           int segElem, char* ldsBase, int tid) {
#pragma unroll
    for (int i = 0; i < 2; ++i) {
        int o = i * 8192 + tid * 16;
        int row = o >> 6;
        int gp  = (o >> 4) & 3;
        int g   = gp ^ ((row >> 1) & 3);
        const char* gsrc = (const char*)src + (size_t)(rowBase + row) * 1024
                         + (size_t)segElem * 2 + g * 16;
        gload_lds16(gsrc, ldsBase + i * 8192 + (tid >> 6) * 1024);
    }
}

#define STAGE2(STKT, STISB) do {                                               \
    int sk_ = (STKT) & (NKT - 1);                                              \
    int se_ = sk_ << 5;                                                        \
    const ushort* sp_ = (STISB) ? ch : xh;                                     \
    int rb_ = (STISB) ? colBase : rowBase;                                     \
    stage_half(sp_, rb_, se_, ldsc + LDSOFF2((sk_ & 1), (STISB)), tid);        \
} while (0)

__launch_bounds__(512, 4)
__global__ void score_mfma8(const ushort* __restrict__ xh, const ushort* __restrict__ ch,
                            const float* __restrict__ xn2, const float* __restrict__ cn2,
                            float* __restrict__ pV1, float* __restrict__ pV2,
                            int* __restrict__ pI1) {
    __shared__ __align__(16) ushort LDSarr[32768];   // 64 KiB
    char* ldsc = (char*)LDSarr;

    int bid = blockIdx.x;                    // 512 blocks, 512 % 8 == 0
    int swz = (bid & 7) * 64 + (bid >> 3);   // XCD-aware
    int tileN = swz & 15;                    // 16 N tiles (4096/256)
    int tileM = swz >> 4;                    // 32 M tiles (8192/256)
    int rowBase = tileM * 256, colBase = tileN * 256;

    int tid = threadIdx.x, lane = tid & 63, w = tid >> 6;
    int wr = w >> 2, wc = w & 3;             // 2M x 4N wave grid
    int g = lane >> 4, c15 = lane & 15;

    f32x4 acc[8][4];
#pragma unroll
    for (int m = 0; m < 8; m++)
#pragma unroll
        for (int n = 0; n < 4; n++) acc[m][n] = (f32x4){0.f, 0.f, 0.f, 0.f};

    f16x8 af_[4], bf_[4];

    // prologue: T0 (A,B) + T1 (A,B) = 8 thread-instrs; vmcnt(4) -> T0 landed
    STAGE2(0, 0); STAGE2(0, 1); STAGE2(1, 0); STAGE2(1, 1);
    __builtin_amdgcn_sched_barrier(0);
    asm volatile("s_waitcnt vmcnt(4)");
    __builtin_amdgcn_sched_barrier(0);
    __builtin_amdgcn_s_barrier();

    for (int kt = 0; kt < NKT; ++kt) {
        int buf = kt & 1;
        // ---- phase 1: A-low + B frags, MFMA into acc[0..3] ----
        __builtin_amdgcn_sched_barrier(0);
#pragma unroll
        for (int m_ = 0; m_ < 4; ++m_)
            af_[m_] = read_frag(ldsc + LDSOFF2(buf, 0), wr * 128 + m_ * 16 + c15, g);
#pragma unroll
        for (int n_ = 0; n_ < 4; ++n_)
            bf_[n_] = read_frag(ldsc + LDSOFF2(buf, 1), wc * 64 + n_ * 16 + c15, g);
        __builtin_amdgcn_sched_barrier(0);
        asm volatile("s_waitcnt lgkmcnt(0)");
        __builtin_amdgcn_sched_barrier(0);
        __builtin_amdgcn_s_setprio(1);
#pragma unroll
        for (int m_ = 0; m_ < 4; ++m_)
#pragma unroll
            for (int n_ = 0; n_ < 4; ++n_)
                acc[m_][n_] = __builtin_amdgcn_mfma_f32_16x16x32_f16(
                    af_[m_], bf_[n_], acc[m_][n_], 0, 0, 0);
        __builtin_amdgcn_s_setprio(0);
        __builtin_amdgcn_sched_barrier(0);
        // ---- phase 2: A-high frags, MFMA into acc[4..7] ----
#pragma unroll
        for (int m_ = 0; m_ < 4; ++m_)
            af_[m_] = read_frag(ldsc + LDSOFF2(buf, 0), wr * 128 + 64 + m_ * 16 + c15, g);
        __builtin_amdgcn_sched_barrier(0);
        asm volatile("s_waitcnt lgkmcnt(0)");
        __builtin_amdgcn_sched_barrier(0);
        __builtin_amdgcn_s_setprio(1);
#pragma unroll
        for (int m_ = 0; m_ < 4; ++m_)
#pragma unroll
            for (int n_ = 0; n_ < 4; ++n_)
                acc[4 + m_][n_] = __builtin_amdgcn_mfma_f32_16x16x32_f16(
                    af_[m_], bf_[n_], acc[4 + m_][n_], 0, 0, 0);
        __builtin_amdgcn_s_setprio(0);
        __builtin_amdgcn_sched_barrier(0);
        // ---- all reads of buf complete across block; stage (kt+2) into it ---
        __builtin_amdgcn_s_barrier();
        STAGE2(kt + 2, 0); STAGE2(kt + 2, 1);
        __builtin_amdgcn_sched_barrier(0);
        asm volatile("s_waitcnt vmcnt(4)");   // (kt+1) pair landed
        __builtin_amdgcn_sched_barrier(0);
        __builtin_amdgcn_s_barrier();
    }

    __syncthreads();   // full drain (vmcnt+lgkm); LDS reused for reduction

    // epilogue: per-(row, 64-code-group) (min1, idx1, min2); group = tileN*4+wc
    float* rv1 = (float*)ldsc;            // [256][4]
    float* rv2 = rv1 + 1024;              // [256][4]
    int*   ri1 = (int*)(rv1 + 2048);      // [256][4]

    float cnv[4];
#pragma unroll
    for (int n = 0; n < 4; ++n) cnv[n] = cn2[colBase + wc * 64 + n * 16 + c15];

#pragma unroll
    for (int m = 0; m < 8; ++m) {
#pragma unroll
        for (int j = 0; j < 4; ++j) {
            int rl = wr * 128 + m * 16 + g * 4 + j;
            float xn = xn2[rowBase + rl];
            float v1 = 3.402823466e38f, v2 = 3.402823466e38f; int i1 = 0x7fffffff;
#pragma unroll
            for (int n = 0; n < 4; ++n) {
                float s = xn + cnv[n] - 2.f * acc[m][n][j];
                int ci = colBase + wc * 64 + n * 16 + c15;
                if (s < v1 || (s == v1 && ci < i1)) { v2 = v1; v1 = s; i1 = ci; }
                else if (s < v2) v2 = s;
            }
#pragma unroll
            for (int off = 1; off < 16; off <<= 1) {
                float ov1 = __shfl_xor(v1, off);
                int   oi1 = __shfl_xor(i1, off);
                float ov2 = __shfl_xor(v2, off);
                if (ov1 < v1 || (ov1 == v1 && oi1 < i1)) {
                    v2 = fminf(v1, ov2); v1 = ov1; i1 = oi1;
                } else {
                    v2 = fminf(v2, ov1);
                }
            }
            if (c15 == 0) {
                rv1[rl * 4 + wc] = v1; rv2[rl * 4 + wc] = v2; ri1[rl * 4 + wc] = i1;
            }
        }
    }
    __syncthreads();
    if (tid < 256) {
#pragma unroll
        for (int t = 0; t < 4; ++t) {
            size_t o = (size_t)(tileN * 4 + t) * R_ROWS + (rowBase + tid);
            pV1[o] = rv1[tid * 4 + t];
            pV2[o] = rv2[tid * 4 + t];
            pI1[o] = ri1[tid * 4 + t];
        }
    }
}

// ------------- combine per-group partials -> idx + near-tie flag ------------
__global__ void combine_flag(const float* __restrict__ pV1, const float* __restrict__ pV2,
                             const int* __restrict__ pI1,
                             int* __restrict__ idx, float* __restrict__ idxF,
                             int* __restrict__ flag, float* __restrict__ vminOut) {
    int r = blockIdx.x * blockDim.x + threadIdx.x;
    if (r >= R_ROWS) return;
    float v1 = 3.402823466e38f, v2 = 3.402823466e38f; int i1 = 0x7fffffff;
    for (int t = 0; t < 64; ++t) {
        float a1 = pV1[(size_t)t * R_ROWS + r];
        float a2 = pV2[(size_t)t * R_ROWS + r];
        int   ai = pI1[(size_t)t * R_ROWS + r];
        if (a1 < v1 || (a1 == v1 && ai < i1)) { v2 = fminf(v1, a2); v1 = a1; i1 = ai; }
        else { v2 = fminf(v2, a1); }
    }
    idx[r] = i1;
    idxF[r] = (float)i1;
    vminOut[r] = v1;
    flag[r] = (v2 - v1 < MARGIN) ? 1 : 0;
}

// ------------- exact f32 re-score of flagged rows, group-filtered -----------
__launch_bounds__(256)
__global__ void refine_rows(const float* __restrict__ x, const float* __restrict__ cb,
                            const float* __restrict__ xn2, const float* __restrict__ cn2,
                            const float* __restrict__ pV1, const float* __restrict__ vmin,
                            const int* __restrict__ flag,
                            int* __restrict__ idx, float* __restrict__ idxF) {
    int r = blockIdx.x;
    if (flag[r] == 0) return;

    __shared__ float xs[DIM];
    __shared__ float wv[4];
    __shared__ int   wi[4];
    __shared__ unsigned long long maskS;
    int tid = threadIdx.x, lane = tid & 63, w = tid >> 6;

    for (int i = tid; i < DIM; i += 256) xs[i] = x[(size_t)r * DIM + i];

    float thr = vmin[r] + TILE_MARGIN;
    if (tid < 64) {   // wave 0 exactly
        float gm = pV1[(size_t)tid * R_ROWS + r];
        unsigned long long b = __ballot(gm <= thr);
        if (tid == 0) maskS = b;
    }
    __syncthreads();

    float x0 = xs[lane * 4 + 0], x1 = xs[lane * 4 + 1];
    float x2 = xs[lane * 4 + 2], x3 = xs[lane * 4 + 3];
    float y0 = xs[256 + lane * 4 + 0], y1 = xs[256 + lane * 4 + 1];
    float y2 = xs[256 + lane * 4 + 2], y3 = xs[256 + lane * 4 + 3];

    float xn = xn2[r];
    float v1 = 3.402823466e38f; int i1 = 0x7fffffff;

    unsigned long long mask = maskS;
    while (mask) {
        int gq = __ffsll((long long)mask) - 1;
        mask &= mask - 1;
        for (int cc = w; cc < 64; cc += 4) {
            int c = gq * 64 + cc;
            const float4* cr = reinterpret_cast<const float4*>(cb + (size_t)c * DIM);
            float4 a = cr[lane];
            float4 b = cr[lane + 64];
            float d = fmaf(x0, a.x, fmaf(x1, a.y, fmaf(x2, a.z, fmaf(x3, a.w,
                      fmaf(y0, b.x, fmaf(y1, b.y, fmaf(y2, b.z, y3 * b.w)))))));
#pragma unroll
            for (int o = 32; o; o >>= 1) d += __shfl_xor(d, o);
            float s = xn + cn2[c] - 2.f * d;
            if (s < v1 || (s == v1 && c < i1)) { v1 = s; i1 = c; }
        }
    }
    if (lane == 0) { wv[w] = v1; wi[w] = i1; }
    __syncthreads();
    if (tid == 0) {
        float bv = wv[0]; int bi = wi[0];
#pragma unroll
        for (int k = 1; k < 4; ++k) {
            if (wv[k] < bv || (wv[k] == bv && wi[k] < bi)) { bv = wv[k]; bi = wi[k]; }
        }
        idx[r] = bi; idxF[r] = (float)bi;
    }
}

// ------------- combine per-tile argmin partials (fallback path) -------------
__global__ void argmin_combine(const float* __restrict__ pVal, const int* __restrict__ pIdx,
                               int* __restrict__ idxOut, float* __restrict__ idxFloatOut,
                               int nTiles) {
    int r = blockIdx.x * blockDim.x + threadIdx.x;
    if (r >= R_ROWS) return;
    float bv = 3.402823466e38f; int bi = 0;
    for (int t = 0; t < nTiles; t++) {
        float v = pVal[(size_t)r * nTiles + t];
        if (v < bv) { bv = v; bi = pIdx[(size_t)r * nTiles + t]; }
    }
    idxOut[r] = bi;
    idxFloatOut[r] = (float)bi;
}

// ------------- rotation trick, one wave per row -----------------------------
__global__ void rotate_rows(const float* __restrict__ x, const float* __restrict__ cb,
                            const int* __restrict__ idx, float* __restrict__ out,
                            float* __restrict__ lossPartial) {
    int gw = (blockIdx.x * blockDim.x + threadIdx.x) >> 6;
    int lane = threadIdx.x & 63;
    if (gw >= R_ROWS) return;

    const float4* x4 = reinterpret_cast<const float4*>(x + (size_t)gw * DIM);
    float4 xa = x4[lane], xb = x4[lane + 64];
    int ci = idx[gw];
    const float4* q4 = reinterpret_cast<const float4*>(cb + (size_t)ci * DIM);
    float4 qa = q4[lane], qb = q4[lane + 64];

    float xe[8] = {xa.x, xa.y, xa.z, xa.w, xb.x, xb.y, xb.z, xb.w};
    float qe[8] = {qa.x, qa.y, qa.z, qa.w, qb.x, qb.y, qb.z, qb.w};

    auto wsum = [&](float v) {
#pragma unroll
        for (int o = 32; o; o >>= 1) v += __shfl_xor(v, o);
        return v;
    };

    float lx = 0.f, lq = 0.f, ld = 0.f;
#pragma unroll
    for (int e = 0; e < 8; e++) {
        lx += xe[e] * xe[e];
        lq += qe[e] * qe[e];
        float d = xe[e] - qe[e];
        ld += d * d;
    }
    float sx2 = wsum(lx);
    float sq2 = wsum(lq);
    float lp  = wsum(ld);

    float nx = sqrtf(sx2), nq = sqrtf(sq2);
    float inx = 1.f / fmaxf(nx, 1e-6f);
    float inq = 1.f / fmaxf(nq, 1e-6f);

    float ue[8], qh[8], we[8];
    float lw = 0.f;
#pragma unroll
    for (int e = 0; e < 8; e++) {
        ue[e] = xe[e] * inx;
        qh[e] = qe[e] * inq;
        we[e] = ue[e] + qh[e];
        lw += we[e] * we[e];
    }
    float sw2 = wsum(lw);
    float inw = 1.f / fmaxf(sqrtf(sw2), 1e-6f);

    float lew = 0.f, leu = 0.f;
#pragma unroll
    for (int e = 0; e < 8; e++) {
        we[e] *= inw;
        lew += xe[e] * we[e];
        leu += xe[e] * ue[e];
    }
    float ew = wsum(lew);
    float eu = wsum(leu);

    float scale = nq / fmaxf(nx, 1e-6f);
    float oe[8];
#pragma unroll
    for (int e = 0; e < 8; e++)
        oe[e] = (xe[e] - 2.f * ew * we[e] + 2.f * eu * qh[e]) * scale;

    float4* o4 = reinterpret_cast<float4*>(out + (size_t)gw * DIM);
    o4[lane]      = make_float4(oe[0], oe[1], oe[2], oe[3]);
    o4[lane + 64] = make_float4(oe[4], oe[5], oe[6], oe[7]);

    if (lane == 0) lossPartial[gw] = lp;
}

// ------------- final loss reduction -----------------------------------------
__global__ void loss_reduce(const float* __restrict__ lp, float* __restrict__ outScalar) {
    __shared__ float red[256];
    float s = 0.f;
    for (int i = threadIdx.x; i < R_ROWS; i += 256) s += lp[i];
    red[threadIdx.x] = s;
    __syncthreads();
    for (int o = 128; o; o >>= 1) {
        if (threadIdx.x < o) red[threadIdx.x] += red[threadIdx.x + o];
        __syncthreads();
    }
    if (threadIdx.x == 0)
        outScalar[0] = 1.25f * red[0] / (float)(R_ROWS * DIM);
}

extern "C" void kernel_launch(void* const* d_in, const int* in_sizes, int n_in,
                              void* d_out, int out_size, void* d_ws, size_t ws_size,
                              hipStream_t stream) {
    const float* x      = (const float*)d_in[0];   // [8192, 512]
    const float* frozen = (const float*)d_in[1];   // [4096, 512]
    const float* weight = (const float*)d_in[2];   // [512, 512]
    float* out = (float*)d_out;

    // ---- workspace layout (MFMA path), ~29 MB ----
    char* p = (char*)d_ws;
    float* cb  = (float*)p;            p += (size_t)NCODES * DIM * 4;
    ushort* xh = (ushort*)p;           p += (size_t)R_ROWS * DIM * 2;
    ushort* ch = (ushort*)p;           p += (size_t)NCODES * DIM * 2;
    float* cn2 = (float*)p;            p += NCODES * 4;
    float* xn2 = (float*)p;            p += R_ROWS * 4;
    float* pV1 = (float*)p;            p += (size_t)R_ROWS * 64 * 4;   // [64][8192]
    float* pV2 = (float*)p;            p += (size_t)R_ROWS * 64 * 4;
    int*   pI1 = (int*)p;              p += (size_t)R_ROWS * 64 * 4;
    int*   idx = (int*)p;              p += R_ROWS * 4;
    int*   flg = (int*)p;              p += R_ROWS * 4;
    float* vmn = (float*)p;            p += R_ROWS * 4;
    float* lp  = (float*)p;            p += R_ROWS * 4;
    size_t need = (size_t)(p - (char*)d_ws);

    if (ws_size >= need) {
        // 1. codebook = frozen @ W^T : f32 GEMM (round-6 bits)
        dim3 g1(DIM / 64, NCODES / 64);
        gemm_nt<64, 64, 4, 4, false><<<g1, 256, 0, stream>>>(
            frozen, weight, cb, nullptr, nullptr, nullptr, nullptr, NCODES, DIM, DIM);

        // 2. exact row norms (round-6 bits)
        rowsumsq<<<NCODES / 4, 256, 0, stream>>>(cb, cn2, NCODES);
        rowsumsq<<<R_ROWS / 4, 256, 0, stream>>>(x, xn2, R_ROWS);

        // 3. f16 casts
        cast_f16<<<(R_ROWS * DIM / 8) / 256, 256, 0, stream>>>(x, xh, R_ROWS * DIM / 8);
        cast_f16<<<(NCODES * DIM / 8) / 256, 256, 0, stream>>>(cb, ch, NCODES * DIM / 8);

        // 4. 1-term f16 MFMA score GEMM + per-group (min1, idx1, min2)
        score_mfma8<<<(R_ROWS / 256) * (NCODES / 256), 512, 0, stream>>>(
            xh, ch, xn2, cn2, pV1, pV2, pI1);

        // 5. combine + near-tie flag
        combine_flag<<<R_ROWS / 256, 256, 0, stream>>>(
            pV1, pV2, pI1, idx, out + (size_t)R_ROWS * DIM, flg, vmn);

        // 6. exact f32 re-score of flagged rows (group-filtered, coalesced)
        refine_rows<<<R_ROWS, 256, 0, stream>>>(
            x, cb, xn2, cn2, pV1, vmn, flg, idx, out + (size_t)R_ROWS * DIM);

        // 7. rotation trick + loss
        rotate_rows<<<R_ROWS / 4, 256, 0, stream>>>(x, cb, idx, out, lp);
        loss_reduce<<<1, 256, 0, stream>>>(lp, out + ((size_t)R_ROWS * DIM + R_ROWS));
    } else {
        // fallback: proven f32 path (~11 MB)
        float* fcn2 = (float*)((char*)d_ws + (size_t)NCODES * DIM * 4);
        float* fxn2 = fcn2 + NCODES;
        float* fpV = fxn2 + R_ROWS;
        int*   fpI = (int*)(fpV + (size_t)R_ROWS * 32);
        int*   fidx = (int*)(fpI + (size_t)R_ROWS * 32);
        float* flp = (float*)(fidx + R_ROWS);
        dim3 g1(DIM / 64, NCODES / 64);
        gemm_nt<64, 64, 4, 4, false><<<g1, 256, 0, stream>>>(
            frozen, weight, cb, nullptr, nullptr, nullptr, nullptr, NCODES, DIM, DIM);
        rowsumsq<<<NCODES / 4, 256, 0, stream>>>(cb, fcn2, NCODES);
        rowsumsq<<<R_ROWS / 4, 256, 0, stream>>>(x, fxn2, R_ROWS);
        dim3 g2(NCODES / 128, R_ROWS / 128);
        gemm_nt<128, 128, 8, 8, true><<<g2, 256, 0, stream>>>(
            x, cb, nullptr, fxn2, fcn2, fpV, fpI, R_ROWS, NCODES, DIM);
        argmin_combine<<<R_ROWS / 256, 256, 0, stream>>>(
            fpV, fpI, fidx, out + (size_t)R_ROWS * DIM, NCODES / 128);
        rotate_rows<<<R_ROWS / 4, 256, 0, stream>>>(x, cb, fidx, out, flp);
        loss_reduce<<<1, 256, 0, stream>>>(flp, out + ((size_t)R_ROWS * DIM + R_ROWS));
    }
}

// Round 12
// 216.921 us; speedup vs baseline: 2.0133x; 2.0133x over previous
//
#include <hip/hip_runtime.h>
#include <hip/hip_bf16.h>
#include <cstdint>

// SimVQ forward: b=8, n=1024 (R=8192 rows), dim=512, codes C=4096.
// Outputs flat f32: rotated [8192*512], indices-as-float [8192], loss [1].
//
// Round-12: r11's BK=32 / 64-KiB-LDS score kernel (race-free, HW-verified in
// r11) with the VGPR cap REMOVED: __launch_bounds__(512,2) like r10 (116
// VGPR, no spill). 116 <= 128 => HW allows 16 waves/CU; LDS 64KiB*2 <= 160
// => 2 blocks/CU co-resident, one scheduling round, per-block fixed cost
// overlapped. r11's (512,4) capped VGPR at 128 < needed and spilled acc to
// scratch (VGPR_Count 64, WRITE_SIZE 795 MB, 341 us).
// Margins, cb f32 GEMM, rowsumsq, combine/refine/rotate: r10 bits.

#define R_ROWS 8192
#define DIM    512
#define NCODES 4096
#define BK     16
#define MARGIN      1.5e-2f
#define TILE_MARGIN 1.8e-2f

typedef __attribute__((ext_vector_type(8))) _Float16 f16x8;
typedef __attribute__((ext_vector_type(4))) float f32x4;
typedef __attribute__((ext_vector_type(8))) unsigned short ushort8;

__device__ __forceinline__ void gload_lds16(const void* g, void* l) {
    __builtin_amdgcn_global_load_lds(
        (const __attribute__((address_space(1))) void*)g,
        (__attribute__((address_space(3))) void*)l, 16, 0, 0);
}

// ---------------- generic f32 NT GEMM (cb + fallback) -----------------------
template<int BM, int BN, int TM, int TN, bool ARGMIN>
__launch_bounds__(256)
__global__ void gemm_nt(const float* __restrict__ A, const float* __restrict__ Bm,
                        float* __restrict__ Cout,
                        const float* __restrict__ rowAdd, const float* __restrict__ colAdd,
                        float* __restrict__ pVal, int* __restrict__ pIdx,
                        int M, int N, int K) {
    constexpr int THREADS = (BM / TM) * (BN / TN);
    constexpr int PAD = 4;
    __shared__ float As[BK][BM + PAD];
    __shared__ float Bs[BK][BN + PAD];

    const int tid = threadIdx.x;
    const int tx = tid % (BN / TN);
    const int ty = tid / (BN / TN);
    const int rowBase = blockIdx.y * BM;
    const int colBase = blockIdx.x * BN;

    float acc[TM][TN];
#pragma unroll
    for (int i = 0; i < TM; i++)
#pragma unroll
        for (int j = 0; j < TN; j++) acc[i][j] = 0.f;

    constexpr int A_F4 = BM * BK / 4;
    constexpr int B_F4 = BN * BK / 4;
    const int nK = K / BK;

    for (int kt = 0; kt < nK; ++kt) {
        const int k0 = kt * BK;
#pragma unroll
        for (int f = 0; f < A_F4 / THREADS; ++f) {
            int e = tid + f * THREADS;
            int row = e >> 2;
            int kq = e & 3;
            float4 v = *reinterpret_cast<const float4*>(
                &A[(size_t)(rowBase + row) * K + k0 + kq * 4]);
            As[kq * 4 + 0][row] = v.x; As[kq * 4 + 1][row] = v.y;
            As[kq * 4 + 2][row] = v.z; As[kq * 4 + 3][row] = v.w;
        }
#pragma unroll
        for (int f = 0; f < B_F4 / THREADS; ++f) {
            int e = tid + f * THREADS;
            int row = e >> 2;
            int kq = e & 3;
            float4 v = *reinterpret_cast<const float4*>(
                &Bm[(size_t)(colBase + row) * K + k0 + kq * 4]);
            Bs[kq * 4 + 0][row] = v.x; Bs[kq * 4 + 1][row] = v.y;
            Bs[kq * 4 + 2][row] = v.z; Bs[kq * 4 + 3][row] = v.w;
        }
        __syncthreads();

#pragma unroll
        for (int k = 0; k < BK; k++) {
            float a[TM], b[TN];
#pragma unroll
            for (int i4 = 0; i4 < TM / 4; i4++) {
                float4 v = *reinterpret_cast<const float4*>(&As[k][ty * TM + i4 * 4]);
                a[i4 * 4 + 0] = v.x; a[i4 * 4 + 1] = v.y;
                a[i4 * 4 + 2] = v.z; a[i4 * 4 + 3] = v.w;
            }
#pragma unroll
            for (int j4 = 0; j4 < TN / 4; j4++) {
                float4 v = *reinterpret_cast<const float4*>(&Bs[k][tx * TN + j4 * 4]);
                b[j4 * 4 + 0] = v.x; b[j4 * 4 + 1] = v.y;
                b[j4 * 4 + 2] = v.z; b[j4 * 4 + 3] = v.w;
            }
#pragma unroll
            for (int i = 0; i < TM; i++)
#pragma unroll
                for (int j = 0; j < TN; j++) acc[i][j] = fmaf(a[i], b[j], acc[i][j]);
        }
        __syncthreads();
    }

    if constexpr (!ARGMIN) {
#pragma unroll
        for (int i = 0; i < TM; i++) {
#pragma unroll
            for (int j4 = 0; j4 < TN / 4; j4++) {
                float4 v = make_float4(acc[i][j4 * 4 + 0], acc[i][j4 * 4 + 1],
                                       acc[i][j4 * 4 + 2], acc[i][j4 * 4 + 3]);
                *reinterpret_cast<float4*>(
                    &Cout[(size_t)(rowBase + ty * TM + i) * N + colBase + tx * TN + j4 * 4]) = v;
            }
        }
    } else {
        constexpr int TX = BN / TN;
        __shared__ float rV[BM][TX + 1];
        __shared__ int   rI[BM][TX + 1];
        float xn[TM];
#pragma unroll
        for (int i = 0; i < TM; i++) xn[i] = rowAdd[rowBase + ty * TM + i];
        float cn[TN];
#pragma unroll
        for (int j = 0; j < TN; j++) cn[j] = colAdd[colBase + tx * TN + j];

#pragma unroll
        for (int i = 0; i < TM; i++) {
            float bv = 3.402823466e38f; int bi = 0;
#pragma unroll
            for (int j = 0; j < TN; j++) {
                float s = xn[i] + cn[j] - 2.f * acc[i][j];
                if (s < bv) { bv = s; bi = colBase + tx * TN + j; }
            }
            rV[ty * TM + i][tx] = bv;
            rI[ty * TM + i][tx] = bi;
        }
        __syncthreads();
        if (tid < BM) {
            float bv = 3.402823466e38f; int bi = 0;
#pragma unroll
            for (int t = 0; t < TX; t++) {
                float v = rV[tid][t];
                if (v < bv) { bv = v; bi = rI[tid][t]; }
            }
            int gr = rowBase + tid;
            pVal[(size_t)gr * gridDim.x + blockIdx.x] = bv;
            pIdx[(size_t)gr * gridDim.x + blockIdx.x] = bi;
        }
    }
}

// ------------- per-row sum of squares (r6 bits) -----------------------------
__global__ void rowsumsq(const float* __restrict__ src, float* __restrict__ dst, int nRows) {
    int gw = (blockIdx.x * blockDim.x + threadIdx.x) >> 6;
    int lane = threadIdx.x & 63;
    if (gw >= nRows) return;
    const float4* s4 = reinterpret_cast<const float4*>(src + (size_t)gw * DIM);
    float4 a = s4[lane];
    float4 b = s4[lane + 64];
    float s = a.x * a.x + a.y * a.y + a.z * a.z + a.w * a.w
            + b.x * b.x + b.y * b.y + b.z * b.z + b.w * b.w;
#pragma unroll
    for (int o = 32; o; o >>= 1) s += __shfl_xor(s, o);
    if (lane == 0) dst[gw] = s;
}

// ------------- f32 -> f16 cast (8 elems / thread) ---------------------------
__global__ void cast_f16(const float* __restrict__ src, ushort* __restrict__ dst, int n8) {
    int t = blockIdx.x * blockDim.x + threadIdx.x;
    if (t >= n8) return;
    float4 a = reinterpret_cast<const float4*>(src)[(size_t)t * 2];
    float4 b = reinterpret_cast<const float4*>(src)[(size_t)t * 2 + 1];
    float v[8] = {a.x, a.y, a.z, a.w, b.x, b.y, b.z, b.w};
    ushort8 h;
#pragma unroll
    for (int e = 0; e < 8; ++e) {
        _Float16 hv = (_Float16)v[e];
        h[e] = *reinterpret_cast<unsigned short*>(&hv);
    }
    reinterpret_cast<ushort8*>(dst)[t] = h;
}

// ================= 256x256 MFMA f16 score GEMM, BK=32, 64KB LDS ==============
// [8192 x 512]f16 * [4096 x 512]f16^T. 16 K-tiles of 32. 8 waves (2M x 4N).
// LDS 64 KiB: 2 buf x (A,B) x 16 KB; each half = [256 rows][32 elems], 64B
// rows, g-XOR bank swizzle (r5-verified). 2 phases/tile; stages for (kt+2)
// issue AFTER the post-MFMA barrier (all reads of target buffer provably
// complete). vmcnt(4) per tile => (kt+1) pair landed, (kt+2) pair in flight.
// Structure HW-verified race-free in r11 (passed, only spilled).

#define NKT 16
#define LDSOFF2(BUF, ISB) ((BUF) * 32768 + (ISB) * 16384)

__device__ __forceinline__ f16x8 read_frag(const char* half_base, int row, int g) {
    int gp = g ^ ((row >> 1) & 3);
    return *reinterpret_cast<const f16x8*>(half_base + row * 64 + gp * 16);
}

__device__ __forceinline__ void stage_half(const ushort* __restrict__ src, int rowBase,
                                           int segElem, char* ldsBase, int tid) {
#pragma unroll
    for (int i = 0; i < 2; ++i) {
        int o = i * 8192 + tid * 16;
        int row = o >> 6;
        int gp  = (o >> 4) & 3;
        int g   = gp ^ ((row >> 1) & 3);
        const char* gsrc = (const char*)src + (size_t)(rowBase + row) * 1024
                         + (size_t)segElem * 2 + g * 16;
        gload_lds16(gsrc, ldsBase + i * 8192 + (tid >> 6) * 1024);
    }
}

#define STAGE2(STKT, STISB) do {                                               \
    int sk_ = (STKT) & (NKT - 1);                                              \
    int se_ = sk_ << 5;                                                        \
    const ushort* sp_ = (STISB) ? ch : xh;                                     \
    int rb_ = (STISB) ? colBase : rowBase;                                     \
    stage_half(sp_, rb_, se_, ldsc + LDSOFF2((sk_ & 1), (STISB)), tid);        \
} while (0)

__launch_bounds__(512, 2)
__global__ void score_mfma8(const ushort* __restrict__ xh, const ushort* __restrict__ ch,
                            const float* __restrict__ xn2, const float* __restrict__ cn2,
                            float* __restrict__ pV1, float* __restrict__ pV2,
                            int* __restrict__ pI1) {
    __shared__ __align__(16) ushort LDSarr[32768];   // 64 KiB
    char* ldsc = (char*)LDSarr;

    int bid = blockIdx.x;                    // 512 blocks, 512 % 8 == 0
    int swz = (bid & 7) * 64 + (bid >> 3);   // XCD-aware
    int tileN = swz & 15;                    // 16 N tiles (4096/256)
    int tileM = swz >> 4;                    // 32 M tiles (8192/256)
    int rowBase = tileM * 256, colBase = tileN * 256;

    int tid = threadIdx.x, lane = tid & 63, w = tid >> 6;
    int wr = w >> 2, wc = w & 3;             // 2M x 4N wave grid
    int g = lane >> 4, c15 = lane & 15;

    f32x4 acc[8][4];
#pragma unroll
    for (int m = 0; m < 8; m++)
#pragma unroll
        for (int n = 0; n < 4; n++) acc[m][n] = (f32x4){0.f, 0.f, 0.f, 0.f};

    f16x8 af_[4], bf_[4];

    // prologue: T0 (A,B) + T1 (A,B) = 8 thread-instrs; vmcnt(4) -> T0 landed
    STAGE2(0, 0); STAGE2(0, 1); STAGE2(1, 0); STAGE2(1, 1);
    __builtin_amdgcn_sched_barrier(0);
    asm volatile("s_waitcnt vmcnt(4)");
    __builtin_amdgcn_sched_barrier(0);
    __builtin_amdgcn_s_barrier();

    for (int kt = 0; kt < NKT; ++kt) {
        int buf = kt & 1;
        // ---- phase 1: A-low + B frags, MFMA into acc[0..3] ----
        __builtin_amdgcn_sched_barrier(0);
#pragma unroll
        for (int m_ = 0; m_ < 4; ++m_)
            af_[m_] = read_frag(ldsc + LDSOFF2(buf, 0), wr * 128 + m_ * 16 + c15, g);
#pragma unroll
        for (int n_ = 0; n_ < 4; ++n_)
            bf_[n_] = read_frag(ldsc + LDSOFF2(buf, 1), wc * 64 + n_ * 16 + c15, g);
        __builtin_amdgcn_sched_barrier(0);
        asm volatile("s_waitcnt lgkmcnt(0)");
        __builtin_amdgcn_sched_barrier(0);
        __builtin_amdgcn_s_setprio(1);
#pragma unroll
        for (int m_ = 0; m_ < 4; ++m_)
#pragma unroll
            for (int n_ = 0; n_ < 4; ++n_)
                acc[m_][n_] = __builtin_amdgcn_mfma_f32_16x16x32_f16(
                    af_[m_], bf_[n_], acc[m_][n_], 0, 0, 0);
        __builtin_amdgcn_s_setprio(0);
        __builtin_amdgcn_sched_barrier(0);
        // ---- phase 2: A-high frags, MFMA into acc[4..7] ----
#pragma unroll
        for (int m_ = 0; m_ < 4; ++m_)
            af_[m_] = read_frag(ldsc + LDSOFF2(buf, 0), wr * 128 + 64 + m_ * 16 + c15, g);
        __builtin_amdgcn_sched_barrier(0);
        asm volatile("s_waitcnt lgkmcnt(0)");
        __builtin_amdgcn_sched_barrier(0);
        __builtin_amdgcn_s_setprio(1);
#pragma unroll
        for (int m_ = 0; m_ < 4; ++m_)
#pragma unroll
            for (int n_ = 0; n_ < 4; ++n_)
                acc[4 + m_][n_] = __builtin_amdgcn_mfma_f32_16x16x32_f16(
                    af_[m_], bf_[n_], acc[4 + m_][n_], 0, 0, 0);
        __builtin_amdgcn_s_setprio(0);
        __builtin_amdgcn_sched_barrier(0);
        // ---- all reads of buf complete across block; stage (kt+2) into it ---
        __builtin_amdgcn_s_barrier();
        STAGE2(kt + 2, 0); STAGE2(kt + 2, 1);
        __builtin_amdgcn_sched_barrier(0);
        asm volatile("s_waitcnt vmcnt(4)");   // (kt+1) pair landed
        __builtin_amdgcn_sched_barrier(0);
        __builtin_amdgcn_s_barrier();
    }

    __syncthreads();   // full drain (vmcnt+lgkm); LDS reused for reduction

    // epilogue: per-(row, 64-code-group) (min1, idx1, min2); group = tileN*4+wc
    float* rv1 = (float*)ldsc;            // [256][4]
    float* rv2 = rv1 + 1024;              // [256][4]
    int*   ri1 = (int*)(rv1 + 2048);      // [256][4]

    float cnv[4];
#pragma unroll
    for (int n = 0; n < 4; ++n) cnv[n] = cn2[colBase + wc * 64 + n * 16 + c15];

#pragma unroll
    for (int m = 0; m < 8; ++m) {
#pragma unroll
        for (int j = 0; j < 4; ++j) {
            int rl = wr * 128 + m * 16 + g * 4 + j;
            float xn = xn2[rowBase + rl];
            float v1 = 3.402823466e38f, v2 = 3.402823466e38f; int i1 = 0x7fffffff;
#pragma unroll
            for (int n = 0; n < 4; ++n) {
                float s = xn + cnv[n] - 2.f * acc[m][n][j];
                int ci = colBase + wc * 64 + n * 16 + c15;
                if (s < v1 || (s == v1 && ci < i1)) { v2 = v1; v1 = s; i1 = ci; }
                else if (s < v2) v2 = s;
            }
#pragma unroll
            for (int off = 1; off < 16; off <<= 1) {
                float ov1 = __shfl_xor(v1, off);
                int   oi1 = __shfl_xor(i1, off);
                float ov2 = __shfl_xor(v2, off);
                if (ov1 < v1 || (ov1 == v1 && oi1 < i1)) {
                    v2 = fminf(v1, ov2); v1 = ov1; i1 = oi1;
                } else {
                    v2 = fminf(v2, ov1);
                }
            }
            if (c15 == 0) {
                rv1[rl * 4 + wc] = v1; rv2[rl * 4 + wc] = v2; ri1[rl * 4 + wc] = i1;
            }
        }
    }
    __syncthreads();
    if (tid < 256) {
#pragma unroll
        for (int t = 0; t < 4; ++t) {
            size_t o = (size_t)(tileN * 4 + t) * R_ROWS + (rowBase + tid);
            pV1[o] = rv1[tid * 4 + t];
            pV2[o] = rv2[tid * 4 + t];
            pI1[o] = ri1[tid * 4 + t];
        }
    }
}

// ------------- combine per-group partials -> idx + near-tie flag ------------
__global__ void combine_flag(const float* __restrict__ pV1, const float* __restrict__ pV2,
                             const int* __restrict__ pI1,
                             int* __restrict__ idx, float* __restrict__ idxF,
                             int* __restrict__ flag, float* __restrict__ vminOut) {
    int r = blockIdx.x * blockDim.x + threadIdx.x;
    if (r >= R_ROWS) return;
    float v1 = 3.402823466e38f, v2 = 3.402823466e38f; int i1 = 0x7fffffff;
    for (int t = 0; t < 64; ++t) {
        float a1 = pV1[(size_t)t * R_ROWS + r];
        float a2 = pV2[(size_t)t * R_ROWS + r];
        int   ai = pI1[(size_t)t * R_ROWS + r];
        if (a1 < v1 || (a1 == v1 && ai < i1)) { v2 = fminf(v1, a2); v1 = a1; i1 = ai; }
        else { v2 = fminf(v2, a1); }
    }
    idx[r] = i1;
    idxF[r] = (float)i1;
    vminOut[r] = v1;
    flag[r] = (v2 - v1 < MARGIN) ? 1 : 0;
}

// ------------- exact f32 re-score of flagged rows, group-filtered -----------
__launch_bounds__(256)
__global__ void refine_rows(const float* __restrict__ x, const float* __restrict__ cb,
                            const float* __restrict__ xn2, const float* __restrict__ cn2,
                            const float* __restrict__ pV1, const float* __restrict__ vmin,
                            const int* __restrict__ flag,
                            int* __restrict__ idx, float* __restrict__ idxF) {
    int r = blockIdx.x;
    if (flag[r] == 0) return;

    __shared__ float xs[DIM];
    __shared__ float wv[4];
    __shared__ int   wi[4];
    __shared__ unsigned long long maskS;
    int tid = threadIdx.x, lane = tid & 63, w = tid >> 6;

    for (int i = tid; i < DIM; i += 256) xs[i] = x[(size_t)r * DIM + i];

    float thr = vmin[r] + TILE_MARGIN;
    if (tid < 64) {   // wave 0 exactly
        float gm = pV1[(size_t)tid * R_ROWS + r];
        unsigned long long b = __ballot(gm <= thr);
        if (tid == 0) maskS = b;
    }
    __syncthreads();

    float x0 = xs[lane * 4 + 0], x1 = xs[lane * 4 + 1];
    float x2 = xs[lane * 4 + 2], x3 = xs[lane * 4 + 3];
    float y0 = xs[256 + lane * 4 + 0], y1 = xs[256 + lane * 4 + 1];
    float y2 = xs[256 + lane * 4 + 2], y3 = xs[256 + lane * 4 + 3];

    float xn = xn2[r];
    float v1 = 3.402823466e38f; int i1 = 0x7fffffff;

    unsigned long long mask = maskS;
    while (mask) {
        int gq = __ffsll((long long)mask) - 1;
        mask &= mask - 1;
        for (int cc = w; cc < 64; cc += 4) {
            int c = gq * 64 + cc;
            const float4* cr = reinterpret_cast<const float4*>(cb + (size_t)c * DIM);
            float4 a = cr[lane];
            float4 b = cr[lane + 64];
            float d = fmaf(x0, a.x, fmaf(x1, a.y, fmaf(x2, a.z, fmaf(x3, a.w,
                      fmaf(y0, b.x, fmaf(y1, b.y, fmaf(y2, b.z, y3 * b.w)))))));
#pragma unroll
            for (int o = 32; o; o >>= 1) d += __shfl_xor(d, o);
            float s = xn + cn2[c] - 2.f * d;
            if (s < v1 || (s == v1 && c < i1)) { v1 = s; i1 = c; }
        }
    }
    if (lane == 0) { wv[w] = v1; wi[w] = i1; }
    __syncthreads();
    if (tid == 0) {
        float bv = wv[0]; int bi = wi[0];
#pragma unroll
        for (int k = 1; k < 4; ++k) {
            if (wv[k] < bv || (wv[k] == bv && wi[k] < bi)) { bv = wv[k]; bi = wi[k]; }
        }
        idx[r] = bi; idxF[r] = (float)bi;
    }
}

// ------------- combine per-tile argmin partials (fallback path) -------------
__global__ void argmin_combine(const float* __restrict__ pVal, const int* __restrict__ pIdx,
                               int* __restrict__ idxOut, float* __restrict__ idxFloatOut,
                               int nTiles) {
    int r = blockIdx.x * blockDim.x + threadIdx.x;
    if (r >= R_ROWS) return;
    float bv = 3.402823466e38f; int bi = 0;
    for (int t = 0; t < nTiles; t++) {
        float v = pVal[(size_t)r * nTiles + t];
        if (v < bv) { bv = v; bi = pIdx[(size_t)r * nTiles + t]; }
    }
    idxOut[r] = bi;
    idxFloatOut[r] = (float)bi;
}

// ------------- rotation trick, one wave per row -----------------------------
__global__ void rotate_rows(const float* __restrict__ x, const float* __restrict__ cb,
                            const int* __restrict__ idx, float* __restrict__ out,
                            float* __restrict__ lossPartial) {
    int gw = (blockIdx.x * blockDim.x + threadIdx.x) >> 6;
    int lane = threadIdx.x & 63;
    if (gw >= R_ROWS) return;

    const float4* x4 = reinterpret_cast<const float4*>(x + (size_t)gw * DIM);
    float4 xa = x4[lane], xb = x4[lane + 64];
    int ci = idx[gw];
    const float4* q4 = reinterpret_cast<const float4*>(cb + (size_t)ci * DIM);
    float4 qa = q4[lane], qb = q4[lane + 64];

    float xe[8] = {xa.x, xa.y, xa.z, xa.w, xb.x, xb.y, xb.z, xb.w};
    float qe[8] = {qa.x, qa.y, qa.z, qa.w, qb.x, qb.y, qb.z, qb.w};

    auto wsum = [&](float v) {
#pragma unroll
        for (int o = 32; o; o >>= 1) v += __shfl_xor(v, o);
        return v;
    };

    float lx = 0.f, lq = 0.f, ld = 0.f;
#pragma unroll
    for (int e = 0; e < 8; e++) {
        lx += xe[e] * xe[e];
        lq += qe[e] * qe[e];
        float d = xe[e] - qe[e];
        ld += d * d;
    }
    float sx2 = wsum(lx);
    float sq2 = wsum(lq);
    float lp  = wsum(ld);

    float nx = sqrtf(sx2), nq = sqrtf(sq2);
    float inx = 1.f / fmaxf(nx, 1e-6f);
    float inq = 1.f / fmaxf(nq, 1e-6f);

    float ue[8], qh[8], we[8];
    float lw = 0.f;
#pragma unroll
    for (int e = 0; e < 8; e++) {
        ue[e] = xe[e] * inx;
        qh[e] = qe[e] * inq;
        we[e] = ue[e] + qh[e];
        lw += we[e] * we[e];
    }
    float sw2 = wsum(lw);
    float inw = 1.f / fmaxf(sqrtf(sw2), 1e-6f);

    float lew = 0.f, leu = 0.f;
#pragma unroll
    for (int e = 0; e < 8; e++) {
        we[e] *= inw;
        lew += xe[e] * we[e];
        leu += xe[e] * ue[e];
    }
    float ew = wsum(lew);
    float eu = wsum(leu);

    float scale = nq / fmaxf(nx, 1e-6f);
    float oe[8];
#pragma unroll
    for (int e = 0; e < 8; e++)
        oe[e] = (xe[e] - 2.f * ew * we[e] + 2.f * eu * qh[e]) * scale;

    float4* o4 = reinterpret_cast<float4*>(out + (size_t)gw * DIM);
    o4[lane]      = make_float4(oe[0], oe[1], oe[2], oe[3]);
    o4[lane + 64] = make_float4(oe[4], oe[5], oe[6], oe[7]);

    if (lane == 0) lossPartial[gw] = lp;
}

// ------------- final loss reduction -----------------------------------------
__global__ void loss_reduce(const float* __restrict__ lp, float* __restrict__ outScalar) {
    __shared__ float red[256];
    float s = 0.f;
    for (int i = threadIdx.x; i < R_ROWS; i += 256) s += lp[i];
    red[threadIdx.x] = s;
    __syncthreads();
    for (int o = 128; o; o >>= 1) {
        if (threadIdx.x < o) red[threadIdx.x] += red[threadIdx.x + o];
        __syncthreads();
    }
    if (threadIdx.x == 0)
        outScalar[0] = 1.25f * red[0] / (float)(R_ROWS * DIM);
}

extern "C" void kernel_launch(void* const* d_in, const int* in_sizes, int n_in,
                              void* d_out, int out_size, void* d_ws, size_t ws_size,
                              hipStream_t stream) {
    const float* x      = (const float*)d_in[0];   // [8192, 512]
    const float* frozen = (const float*)d_in[1];   // [4096, 512]
    const float* weight = (const float*)d_in[2];   // [512, 512]
    float* out = (float*)d_out;

    // ---- workspace layout (MFMA path), ~29 MB ----
    char* p = (char*)d_ws;
    float* cb  = (float*)p;            p += (size_t)NCODES * DIM * 4;
    ushort* xh = (ushort*)p;           p += (size_t)R_ROWS * DIM * 2;
    ushort* ch = (ushort*)p;           p += (size_t)NCODES * DIM * 2;
    float* cn2 = (float*)p;            p += NCODES * 4;
    float* xn2 = (float*)p;            p += R_ROWS * 4;
    float* pV1 = (float*)p;            p += (size_t)R_ROWS * 64 * 4;   // [64][8192]
    float* pV2 = (float*)p;            p += (size_t)R_ROWS * 64 * 4;
    int*   pI1 = (int*)p;              p += (size_t)R_ROWS * 64 * 4;
    int*   idx = (int*)p;              p += R_ROWS * 4;
    int*   flg = (int*)p;              p += R_ROWS * 4;
    float* vmn = (float*)p;            p += R_ROWS * 4;
    float* lp  = (float*)p;            p += R_ROWS * 4;
    size_t need = (size_t)(p - (char*)d_ws);

    if (ws_size >= need) {
        // 1. codebook = frozen @ W^T : f32 GEMM (round-6 bits)
        dim3 g1(DIM / 64, NCODES / 64);
        gemm_nt<64, 64, 4, 4, false><<<g1, 256, 0, stream>>>(
            frozen, weight, cb, nullptr, nullptr, nullptr, nullptr, NCODES, DIM, DIM);

        // 2. exact row norms (round-6 bits)
        rowsumsq<<<NCODES / 4, 256, 0, stream>>>(cb, cn2, NCODES);
        rowsumsq<<<R_ROWS / 4, 256, 0, stream>>>(x, xn2, R_ROWS);

        // 3. f16 casts
        cast_f16<<<(R_ROWS * DIM / 8) / 256, 256, 0, stream>>>(x, xh, R_ROWS * DIM / 8);
        cast_f16<<<(NCODES * DIM / 8) / 256, 256, 0, stream>>>(cb, ch, NCODES * DIM / 8);

        // 4. 1-term f16 MFMA score GEMM + per-group (min1, idx1, min2)
        score_mfma8<<<(R_ROWS / 256) * (NCODES / 256), 512, 0, stream>>>(
            xh, ch, xn2, cn2, pV1, pV2, pI1);

        // 5. combine + near-tie flag
        combine_flag<<<R_ROWS / 256, 256, 0, stream>>>(
            pV1, pV2, pI1, idx, out + (size_t)R_ROWS * DIM, flg, vmn);

        // 6. exact f32 re-score of flagged rows (group-filtered, coalesced)
        refine_rows<<<R_ROWS, 256, 0, stream>>>(
            x, cb, xn2, cn2, pV1, vmn, flg, idx, out + (size_t)R_ROWS * DIM);

        // 7. rotation trick + loss
        rotate_rows<<<R_ROWS / 4, 256, 0, stream>>>(x, cb, idx, out, lp);
        loss_reduce<<<1, 256, 0, stream>>>(lp, out + ((size_t)R_ROWS * DIM + R_ROWS));
    } else {
        // fallback: proven f32 path (~11 MB)
        float* fcn2 = (float*)((char*)d_ws + (size_t)NCODES * DIM * 4);
        float* fxn2 = fcn2 + NCODES;
        float* fpV = fxn2 + R_ROWS;
        int*   fpI = (int*)(fpV + (size_t)R_ROWS * 32);
        int*   fidx = (int*)(fpI + (size_t)R_ROWS * 32);
        float* flp = (float*)(fidx + R_ROWS);
        dim3 g1(DIM / 64, NCODES / 64);
        gemm_nt<64, 64, 4, 4, false><<<g1, 256, 0, stream>>>(
            frozen, weight, cb, nullptr, nullptr, nullptr, nullptr, NCODES, DIM, DIM);
        rowsumsq<<<NCODES / 4, 256, 0, stream>>>(cb, fcn2, NCODES);
        rowsumsq<<<R_ROWS / 4, 256, 0, stream>>>(x, fxn2, R_ROWS);
        dim3 g2(NCODES / 128, R_ROWS / 128);
        gemm_nt<128, 128, 8, 8, true><<<g2, 256, 0, stream>>>(
            x, cb, nullptr, fxn2, fcn2, fpV, fpI, R_ROWS, NCODES, DIM);
        argmin_combine<<<R_ROWS / 256, 256, 0, stream>>>(
            fpV, fpI, fidx, out + (size_t)R_ROWS * DIM, NCODES / 128);
        rotate_rows<<<R_ROWS / 4, 256, 0, stream>>>(x, cb, fidx, out, flp);
        loss_reduce<<<1, 256, 0, stream>>>(flp, out + ((size_t)R_ROWS * DIM + R_ROWS));
    }
}

// Round 13
// 210.508 us; speedup vs baseline: 2.0746x; 1.0305x over previous
//
#include <hip/hip_runtime.h>
#include <hip/hip_bf16.h>
#include <cstdint>

// SimVQ forward: b=8, n=1024 (R=8192 rows), dim=512, codes C=4096.
// Outputs flat f32: rotated [8192*512], indices-as-float [8192], loss [1].
//
// Round-13: score kernel re-geometried to LIGHT blocks for latency hiding:
//   128x128 tile, 4 waves (256 thr), 16 KB single-buffer LDS, r2's proven
//   2-__syncthreads loop (compiler drains vmcnt at barrier). 2048 blocks ->
//   ~5 blocks/CU resident (20 waves/CU) vs r12's 8-wave/128KB design stuck
//   at 2 waves/SIMD (57us fixed + 1us/phase latency-bound, r6/r10/r12 fit).
//   g-XOR bank swizzle kept (r5). Group-granular epilogue kept (r10);
//   group = tileN*2+wc (still 64 groups of 64 codes). K-accumulation order
//   unchanged -> identical partials to r12 (PASSING).
// Margins, cb f32 GEMM, rowsumsq, combine/refine/rotate: r10 bits.

#define R_ROWS 8192
#define DIM    512
#define NCODES 4096
#define BK     16
#define MARGIN      1.5e-2f
#define TILE_MARGIN 1.8e-2f

typedef __attribute__((ext_vector_type(8))) _Float16 f16x8;
typedef __attribute__((ext_vector_type(4))) float f32x4;
typedef __attribute__((ext_vector_type(8))) unsigned short ushort8;

__device__ __forceinline__ void gload_lds16(const void* g, void* l) {
    __builtin_amdgcn_global_load_lds(
        (const __attribute__((address_space(1))) void*)g,
        (__attribute__((address_space(3))) void*)l, 16, 0, 0);
}

// ---------------- generic f32 NT GEMM (cb + fallback) -----------------------
template<int BM, int BN, int TM, int TN, bool ARGMIN>
__launch_bounds__(256)
__global__ void gemm_nt(const float* __restrict__ A, const float* __restrict__ Bm,
                        float* __restrict__ Cout,
                        const float* __restrict__ rowAdd, const float* __restrict__ colAdd,
                        float* __restrict__ pVal, int* __restrict__ pIdx,
                        int M, int N, int K) {
    constexpr int THREADS = (BM / TM) * (BN / TN);
    constexpr int PAD = 4;
    __shared__ float As[BK][BM + PAD];
    __shared__ float Bs[BK][BN + PAD];

    const int tid = threadIdx.x;
    const int tx = tid % (BN / TN);
    const int ty = tid / (BN / TN);
    const int rowBase = blockIdx.y * BM;
    const int colBase = blockIdx.x * BN;

    float acc[TM][TN];
#pragma unroll
    for (int i = 0; i < TM; i++)
#pragma unroll
        for (int j = 0; j < TN; j++) acc[i][j] = 0.f;

    constexpr int A_F4 = BM * BK / 4;
    constexpr int B_F4 = BN * BK / 4;
    const int nK = K / BK;

    for (int kt = 0; kt < nK; ++kt) {
        const int k0 = kt * BK;
#pragma unroll
        for (int f = 0; f < A_F4 / THREADS; ++f) {
            int e = tid + f * THREADS;
            int row = e >> 2;
            int kq = e & 3;
            float4 v = *reinterpret_cast<const float4*>(
                &A[(size_t)(rowBase + row) * K + k0 + kq * 4]);
            As[kq * 4 + 0][row] = v.x; As[kq * 4 + 1][row] = v.y;
            As[kq * 4 + 2][row] = v.z; As[kq * 4 + 3][row] = v.w;
        }
#pragma unroll
        for (int f = 0; f < B_F4 / THREADS; ++f) {
            int e = tid + f * THREADS;
            int row = e >> 2;
            int kq = e & 3;
            float4 v = *reinterpret_cast<const float4*>(
                &Bm[(size_t)(colBase + row) * K + k0 + kq * 4]);
            Bs[kq * 4 + 0][row] = v.x; Bs[kq * 4 + 1][row] = v.y;
            Bs[kq * 4 + 2][row] = v.z; Bs[kq * 4 + 3][row] = v.w;
        }
        __syncthreads();

#pragma unroll
        for (int k = 0; k < BK; k++) {
            float a[TM], b[TN];
#pragma unroll
            for (int i4 = 0; i4 < TM / 4; i4++) {
                float4 v = *reinterpret_cast<const float4*>(&As[k][ty * TM + i4 * 4]);
                a[i4 * 4 + 0] = v.x; a[i4 * 4 + 1] = v.y;
                a[i4 * 4 + 2] = v.z; a[i4 * 4 + 3] = v.w;
            }
#pragma unroll
            for (int j4 = 0; j4 < TN / 4; j4++) {
                float4 v = *reinterpret_cast<const float4*>(&Bs[k][tx * TN + j4 * 4]);
                b[j4 * 4 + 0] = v.x; b[j4 * 4 + 1] = v.y;
                b[j4 * 4 + 2] = v.z; b[j4 * 4 + 3] = v.w;
            }
#pragma unroll
            for (int i = 0; i < TM; i++)
#pragma unroll
                for (int j = 0; j < TN; j++) acc[i][j] = fmaf(a[i], b[j], acc[i][j]);
        }
        __syncthreads();
    }

    if constexpr (!ARGMIN) {
#pragma unroll
        for (int i = 0; i < TM; i++) {
#pragma unroll
            for (int j4 = 0; j4 < TN / 4; j4++) {
                float4 v = make_float4(acc[i][j4 * 4 + 0], acc[i][j4 * 4 + 1],
                                       acc[i][j4 * 4 + 2], acc[i][j4 * 4 + 3]);
                *reinterpret_cast<float4*>(
                    &Cout[(size_t)(rowBase + ty * TM + i) * N + colBase + tx * TN + j4 * 4]) = v;
            }
        }
    } else {
        constexpr int TX = BN / TN;
        __shared__ float rV[BM][TX + 1];
        __shared__ int   rI[BM][TX + 1];
        float xn[TM];
#pragma unroll
        for (int i = 0; i < TM; i++) xn[i] = rowAdd[rowBase + ty * TM + i];
        float cn[TN];
#pragma unroll
        for (int j = 0; j < TN; j++) cn[j] = colAdd[colBase + tx * TN + j];

#pragma unroll
        for (int i = 0; i < TM; i++) {
            float bv = 3.402823466e38f; int bi = 0;
#pragma unroll
            for (int j = 0; j < TN; j++) {
                float s = xn[i] + cn[j] - 2.f * acc[i][j];
                if (s < bv) { bv = s; bi = colBase + tx * TN + j; }
            }
            rV[ty * TM + i][tx] = bv;
            rI[ty * TM + i][tx] = bi;
        }
        __syncthreads();
        if (tid < BM) {
            float bv = 3.402823466e38f; int bi = 0;
#pragma unroll
            for (int t = 0; t < TX; t++) {
                float v = rV[tid][t];
                if (v < bv) { bv = v; bi = rI[tid][t]; }
            }
            int gr = rowBase + tid;
            pVal[(size_t)gr * gridDim.x + blockIdx.x] = bv;
            pIdx[(size_t)gr * gridDim.x + blockIdx.x] = bi;
        }
    }
}

// ------------- per-row sum of squares (r6 bits) -----------------------------
__global__ void rowsumsq(const float* __restrict__ src, float* __restrict__ dst, int nRows) {
    int gw = (blockIdx.x * blockDim.x + threadIdx.x) >> 6;
    int lane = threadIdx.x & 63;
    if (gw >= nRows) return;
    const float4* s4 = reinterpret_cast<const float4*>(src + (size_t)gw * DIM);
    float4 a = s4[lane];
    float4 b = s4[lane + 64];
    float s = a.x * a.x + a.y * a.y + a.z * a.z + a.w * a.w
            + b.x * b.x + b.y * b.y + b.z * b.z + b.w * b.w;
#pragma unroll
    for (int o = 32; o; o >>= 1) s += __shfl_xor(s, o);
    if (lane == 0) dst[gw] = s;
}

// ------------- f32 -> f16 cast (8 elems / thread) ---------------------------
__global__ void cast_f16(const float* __restrict__ src, ushort* __restrict__ dst, int n8) {
    int t = blockIdx.x * blockDim.x + threadIdx.x;
    if (t >= n8) return;
    float4 a = reinterpret_cast<const float4*>(src)[(size_t)t * 2];
    float4 b = reinterpret_cast<const float4*>(src)[(size_t)t * 2 + 1];
    float v[8] = {a.x, a.y, a.z, a.w, b.x, b.y, b.z, b.w};
    ushort8 h;
#pragma unroll
    for (int e = 0; e < 8; ++e) {
        _Float16 hv = (_Float16)v[e];
        h[e] = *reinterpret_cast<unsigned short*>(&hv);
    }
    reinterpret_cast<ushort8*>(dst)[t] = h;
}

// ========= 128x128 MFMA f16 score GEMM, 4 waves, 16KB LDS, r2 sync ==========
// [8192 x 512]f16 * [4096 x 512]f16^T. 16 K-chunks of 32. Wave grid 2M x 2N,
// per-wave output 64x64 (acc 4x4 f32x4). Single-buffered As/Bs [128][32]
// (64B rows, g-XOR swizzle). __syncthreads pairs per chunk (proven r2).

__device__ __forceinline__ f16x8 read_frag(const char* half_base, int row, int g) {
    int gp = g ^ ((row >> 1) & 3);
    return *reinterpret_cast<const f16x8*>(half_base + row * 64 + gp * 16);
}

// stage one 8KB tile (128 rows x 32 elems f16): linear LDS dest, g-chunk of
// the global source inverse-permuted (both-sides swizzle, r5-verified).
__device__ __forceinline__ void stage128(const ushort* __restrict__ src, int rowBase,
                                         int segElem, char* ldsBase, int tid) {
#pragma unroll
    for (int i = 0; i < 2; ++i) {
        int o = i * 4096 + tid * 16;          // linear LDS slot (256 thr x 16B)
        int row = o >> 6;                     // 0..127
        int gp  = (o >> 4) & 3;
        int g   = gp ^ ((row >> 1) & 3);
        const char* gsrc = (const char*)src + (size_t)(rowBase + row) * 1024
                         + (size_t)segElem * 2 + g * 16;
        gload_lds16(gsrc, ldsBase + i * 4096 + (tid >> 6) * 1024);
    }
}

__launch_bounds__(256)
__global__ void score_mfma4(const ushort* __restrict__ xh, const ushort* __restrict__ ch,
                            const float* __restrict__ xn2, const float* __restrict__ cn2,
                            float* __restrict__ pV1, float* __restrict__ pV2,
                            int* __restrict__ pI1) {
    __shared__ __align__(16) ushort As[4096];   // 8 KB: [128][32] swizzled
    __shared__ __align__(16) ushort Bs[4096];   // 8 KB

    int bid = blockIdx.x;                    // 2048 blocks, 2048 % 8 == 0
    int swz = (bid & 7) * 256 + (bid >> 3);  // XCD-aware
    int tileN = swz & 31;                    // 32 N tiles (4096/128)
    int tileM = swz >> 5;                    // 64 M tiles (8192/128)
    int rowBase = tileM * 128, colBase = tileN * 128;

    int tid = threadIdx.x, lane = tid & 63, w = tid >> 6;
    int wr = w >> 1, wc = w & 1;             // 2M x 2N wave grid
    int g = lane >> 4, c15 = lane & 15;

    f32x4 acc[4][4];
#pragma unroll
    for (int m = 0; m < 4; m++)
#pragma unroll
        for (int n = 0; n < 4; n++) acc[m][n] = (f32x4){0.f, 0.f, 0.f, 0.f};

    for (int kk = 0; kk < 16; ++kk) {
        int se = kk * 32;
        stage128(xh, rowBase, se, (char*)As, tid);
        stage128(ch, colBase, se, (char*)Bs, tid);
        __syncthreads();   // compiler drains vmcnt before barrier (r2-proven)

        f16x8 af[4], bf[4];
#pragma unroll
        for (int m = 0; m < 4; ++m)
            af[m] = read_frag((const char*)As, wr * 64 + m * 16 + c15, g);
#pragma unroll
        for (int n = 0; n < 4; ++n)
            bf[n] = read_frag((const char*)Bs, wc * 64 + n * 16 + c15, g);
#pragma unroll
        for (int m = 0; m < 4; ++m)
#pragma unroll
            for (int n = 0; n < 4; ++n)
                acc[m][n] = __builtin_amdgcn_mfma_f32_16x16x32_f16(
                    af[m], bf[n], acc[m][n], 0, 0, 0);
        __syncthreads();
    }

    // epilogue: per-(row, 64-code-group); group = tileN*2 + wc (one per wave).
    // No cross-wave reduce needed: a wave's 64 cols ARE one group.
    float cnv[4];
#pragma unroll
    for (int n = 0; n < 4; ++n) cnv[n] = cn2[colBase + wc * 64 + n * 16 + c15];

    size_t gbase = (size_t)(tileN * 2 + wc) * R_ROWS + rowBase;
#pragma unroll
    for (int m = 0; m < 4; ++m) {
#pragma unroll
        for (int j = 0; j < 4; ++j) {
            int rl = wr * 64 + m * 16 + g * 4 + j;
            float xn = xn2[rowBase + rl];
            float v1 = 3.402823466e38f, v2 = 3.402823466e38f; int i1 = 0x7fffffff;
#pragma unroll
            for (int n = 0; n < 4; ++n) {
                float s = xn + cnv[n] - 2.f * acc[m][n][j];
                int ci = colBase + wc * 64 + n * 16 + c15;
                if (s < v1 || (s == v1 && ci < i1)) { v2 = v1; v1 = s; i1 = ci; }
                else if (s < v2) v2 = s;
            }
#pragma unroll
            for (int off = 1; off < 16; off <<= 1) {
                float ov1 = __shfl_xor(v1, off);
                int   oi1 = __shfl_xor(i1, off);
                float ov2 = __shfl_xor(v2, off);
                if (ov1 < v1 || (ov1 == v1 && oi1 < i1)) {
                    v2 = fminf(v1, ov2); v1 = ov1; i1 = oi1;
                } else {
                    v2 = fminf(v2, ov1);
                }
            }
            if (c15 == 0) {
                size_t o = gbase + rl;
                pV1[o] = v1; pV2[o] = v2; pI1[o] = i1;
            }
        }
    }
}

// ------------- combine per-group partials -> idx + near-tie flag ------------
__global__ void combine_flag(const float* __restrict__ pV1, const float* __restrict__ pV2,
                             const int* __restrict__ pI1,
                             int* __restrict__ idx, float* __restrict__ idxF,
                             int* __restrict__ flag, float* __restrict__ vminOut) {
    int r = blockIdx.x * blockDim.x + threadIdx.x;
    if (r >= R_ROWS) return;
    float v1 = 3.402823466e38f, v2 = 3.402823466e38f; int i1 = 0x7fffffff;
    for (int t = 0; t < 64; ++t) {
        float a1 = pV1[(size_t)t * R_ROWS + r];
        float a2 = pV2[(size_t)t * R_ROWS + r];
        int   ai = pI1[(size_t)t * R_ROWS + r];
        if (a1 < v1 || (a1 == v1 && ai < i1)) { v2 = fminf(v1, a2); v1 = a1; i1 = ai; }
        else { v2 = fminf(v2, a1); }
    }
    idx[r] = i1;
    idxF[r] = (float)i1;
    vminOut[r] = v1;
    flag[r] = (v2 - v1 < MARGIN) ? 1 : 0;
}

// ------------- exact f32 re-score of flagged rows, group-filtered -----------
__launch_bounds__(256)
__global__ void refine_rows(const float* __restrict__ x, const float* __restrict__ cb,
                            const float* __restrict__ xn2, const float* __restrict__ cn2,
                            const float* __restrict__ pV1, const float* __restrict__ vmin,
                            const int* __restrict__ flag,
                            int* __restrict__ idx, float* __restrict__ idxF) {
    int r = blockIdx.x;
    if (flag[r] == 0) return;

    __shared__ float xs[DIM];
    __shared__ float wv[4];
    __shared__ int   wi[4];
    __shared__ unsigned long long maskS;
    int tid = threadIdx.x, lane = tid & 63, w = tid >> 6;

    for (int i = tid; i < DIM; i += 256) xs[i] = x[(size_t)r * DIM + i];

    float thr = vmin[r] + TILE_MARGIN;
    if (tid < 64) {   // wave 0 exactly
        float gm = pV1[(size_t)tid * R_ROWS + r];
        unsigned long long b = __ballot(gm <= thr);
        if (tid == 0) maskS = b;
    }
    __syncthreads();

    float x0 = xs[lane * 4 + 0], x1 = xs[lane * 4 + 1];
    float x2 = xs[lane * 4 + 2], x3 = xs[lane * 4 + 3];
    float y0 = xs[256 + lane * 4 + 0], y1 = xs[256 + lane * 4 + 1];
    float y2 = xs[256 + lane * 4 + 2], y3 = xs[256 + lane * 4 + 3];

    float xn = xn2[r];
    float v1 = 3.402823466e38f; int i1 = 0x7fffffff;

    unsigned long long mask = maskS;
    while (mask) {
        int gq = __ffsll((long long)mask) - 1;
        mask &= mask - 1;
        for (int cc = w; cc < 64; cc += 4) {
            int c = gq * 64 + cc;
            const float4* cr = reinterpret_cast<const float4*>(cb + (size_t)c * DIM);
            float4 a = cr[lane];
            float4 b = cr[lane + 64];
            float d = fmaf(x0, a.x, fmaf(x1, a.y, fmaf(x2, a.z, fmaf(x3, a.w,
                      fmaf(y0, b.x, fmaf(y1, b.y, fmaf(y2, b.z, y3 * b.w)))))));
#pragma unroll
            for (int o = 32; o; o >>= 1) d += __shfl_xor(d, o);
            float s = xn + cn2[c] - 2.f * d;
            if (s < v1 || (s == v1 && c < i1)) { v1 = s; i1 = c; }
        }
    }
    if (lane == 0) { wv[w] = v1; wi[w] = i1; }
    __syncthreads();
    if (tid == 0) {
        float bv = wv[0]; int bi = wi[0];
#pragma unroll
        for (int k = 1; k < 4; ++k) {
            if (wv[k] < bv || (wv[k] == bv && wi[k] < bi)) { bv = wv[k]; bi = wi[k]; }
        }
        idx[r] = bi; idxF[r] = (float)bi;
    }
}

// ------------- combine per-tile argmin partials (fallback path) -------------
__global__ void argmin_combine(const float* __restrict__ pVal, const int* __restrict__ pIdx,
                               int* __restrict__ idxOut, float* __restrict__ idxFloatOut,
                               int nTiles) {
    int r = blockIdx.x * blockDim.x + threadIdx.x;
    if (r >= R_ROWS) return;
    float bv = 3.402823466e38f; int bi = 0;
    for (int t = 0; t < nTiles; t++) {
        float v = pVal[(size_t)r * nTiles + t];
        if (v < bv) { bv = v; bi = pIdx[(size_t)r * nTiles + t]; }
    }
    idxOut[r] = bi;
    idxFloatOut[r] = (float)bi;
}

// ------------- rotation trick, one wave per row -----------------------------
__global__ void rotate_rows(const float* __restrict__ x, const float* __restrict__ cb,
                            const int* __restrict__ idx, float* __restrict__ out,
                            float* __restrict__ lossPartial) {
    int gw = (blockIdx.x * blockDim.x + threadIdx.x) >> 6;
    int lane = threadIdx.x & 63;
    if (gw >= R_ROWS) return;

    const float4* x4 = reinterpret_cast<const float4*>(x + (size_t)gw * DIM);
    float4 xa = x4[lane], xb = x4[lane + 64];
    int ci = idx[gw];
    const float4* q4 = reinterpret_cast<const float4*>(cb + (size_t)ci * DIM);
    float4 qa = q4[lane], qb = q4[lane + 64];

    float xe[8] = {xa.x, xa.y, xa.z, xa.w, xb.x, xb.y, xb.z, xb.w};
    float qe[8] = {qa.x, qa.y, qa.z, qa.w, qb.x, qb.y, qb.z, qb.w};

    auto wsum = [&](float v) {
#pragma unroll
        for (int o = 32; o; o >>= 1) v += __shfl_xor(v, o);
        return v;
    };

    float lx = 0.f, lq = 0.f, ld = 0.f;
#pragma unroll
    for (int e = 0; e < 8; e++) {
        lx += xe[e] * xe[e];
        lq += qe[e] * qe[e];
        float d = xe[e] - qe[e];
        ld += d * d;
    }
    float sx2 = wsum(lx);
    float sq2 = wsum(lq);
    float lp  = wsum(ld);

    float nx = sqrtf(sx2), nq = sqrtf(sq2);
    float inx = 1.f / fmaxf(nx, 1e-6f);
    float inq = 1.f / fmaxf(nq, 1e-6f);

    float ue[8], qh[8], we[8];
    float lw = 0.f;
#pragma unroll
    for (int e = 0; e < 8; e++) {
        ue[e] = xe[e] * inx;
        qh[e] = qe[e] * inq;
        we[e] = ue[e] + qh[e];
        lw += we[e] * we[e];
    }
    float sw2 = wsum(lw);
    float inw = 1.f / fmaxf(sqrtf(sw2), 1e-6f);

    float lew = 0.f, leu = 0.f;
#pragma unroll
    for (int e = 0; e < 8; e++) {
        we[e] *= inw;
        lew += xe[e] * we[e];
        leu += xe[e] * ue[e];
    }
    float ew = wsum(lew);
    float eu = wsum(leu);

    float scale = nq / fmaxf(nx, 1e-6f);
    float oe[8];
#pragma unroll
    for (int e = 0; e < 8; e++)
        oe[e] = (xe[e] - 2.f * ew * we[e] + 2.f * eu * qh[e]) * scale;

    float4* o4 = reinterpret_cast<float4*>(out + (size_t)gw * DIM);
    o4[lane]      = make_float4(oe[0], oe[1], oe[2], oe[3]);
    o4[lane + 64] = make_float4(oe[4], oe[5], oe[6], oe[7]);

    if (lane == 0) lossPartial[gw] = lp;
}

// ------------- final loss reduction -----------------------------------------
__global__ void loss_reduce(const float* __restrict__ lp, float* __restrict__ outScalar) {
    __shared__ float red[256];
    float s = 0.f;
    for (int i = threadIdx.x; i < R_ROWS; i += 256) s += lp[i];
    red[threadIdx.x] = s;
    __syncthreads();
    for (int o = 128; o; o >>= 1) {
        if (threadIdx.x < o) red[threadIdx.x] += red[threadIdx.x + o];
        __syncthreads();
    }
    if (threadIdx.x == 0)
        outScalar[0] = 1.25f * red[0] / (float)(R_ROWS * DIM);
}

extern "C" void kernel_launch(void* const* d_in, const int* in_sizes, int n_in,
                              void* d_out, int out_size, void* d_ws, size_t ws_size,
                              hipStream_t stream) {
    const float* x      = (const float*)d_in[0];   // [8192, 512]
    const float* frozen = (const float*)d_in[1];   // [4096, 512]
    const float* weight = (const float*)d_in[2];   // [512, 512]
    float* out = (float*)d_out;

    // ---- workspace layout (MFMA path), ~29 MB ----
    char* p = (char*)d_ws;
    float* cb  = (float*)p;            p += (size_t)NCODES * DIM * 4;
    ushort* xh = (ushort*)p;           p += (size_t)R_ROWS * DIM * 2;
    ushort* ch = (ushort*)p;           p += (size_t)NCODES * DIM * 2;
    float* cn2 = (float*)p;            p += NCODES * 4;
    float* xn2 = (float*)p;            p += R_ROWS * 4;
    float* pV1 = (float*)p;            p += (size_t)R_ROWS * 64 * 4;   // [64][8192]
    float* pV2 = (float*)p;            p += (size_t)R_ROWS * 64 * 4;
    int*   pI1 = (int*)p;              p += (size_t)R_ROWS * 64 * 4;
    int*   idx = (int*)p;              p += R_ROWS * 4;
    int*   flg = (int*)p;              p += R_ROWS * 4;
    float* vmn = (float*)p;            p += R_ROWS * 4;
    float* lp  = (float*)p;            p += R_ROWS * 4;
    size_t need = (size_t)(p - (char*)d_ws);

    if (ws_size >= need) {
        // 1. codebook = frozen @ W^T : f32 GEMM (round-6 bits)
        dim3 g1(DIM / 64, NCODES / 64);
        gemm_nt<64, 64, 4, 4, false><<<g1, 256, 0, stream>>>(
            frozen, weight, cb, nullptr, nullptr, nullptr, nullptr, NCODES, DIM, DIM);

        // 2. exact row norms (round-6 bits)
        rowsumsq<<<NCODES / 4, 256, 0, stream>>>(cb, cn2, NCODES);
        rowsumsq<<<R_ROWS / 4, 256, 0, stream>>>(x, xn2, R_ROWS);

        // 3. f16 casts
        cast_f16<<<(R_ROWS * DIM / 8) / 256, 256, 0, stream>>>(x, xh, R_ROWS * DIM / 8);
        cast_f16<<<(NCODES * DIM / 8) / 256, 256, 0, stream>>>(cb, ch, NCODES * DIM / 8);

        // 4. 1-term f16 MFMA score GEMM (light blocks) + per-group partials
        score_mfma4<<<(R_ROWS / 128) * (NCODES / 128), 256, 0, stream>>>(
            xh, ch, xn2, cn2, pV1, pV2, pI1);

        // 5. combine + near-tie flag
        combine_flag<<<R_ROWS / 256, 256, 0, stream>>>(
            pV1, pV2, pI1, idx, out + (size_t)R_ROWS * DIM, flg, vmn);

        // 6. exact f32 re-score of flagged rows (group-filtered, coalesced)
        refine_rows<<<R_ROWS, 256, 0, stream>>>(
            x, cb, xn2, cn2, pV1, vmn, flg, idx, out + (size_t)R_ROWS * DIM);

        // 7. rotation trick + loss
        rotate_rows<<<R_ROWS / 4, 256, 0, stream>>>(x, cb, idx, out, lp);
        loss_reduce<<<1, 256, 0, stream>>>(lp, out + ((size_t)R_ROWS * DIM + R_ROWS));
    } else {
        // fallback: proven f32 path (~11 MB)
        float* fcn2 = (float*)((char*)d_ws + (size_t)NCODES * DIM * 4);
        float* fxn2 = fcn2 + NCODES;
        float* fpV = fxn2 + R_ROWS;
        int*   fpI = (int*)(fpV + (size_t)R_ROWS * 32);
        int*   fidx = (int*)(fpI + (size_t)R_ROWS * 32);
        float* flp = (float*)(fidx + R_ROWS);
        dim3 g1(DIM / 64, NCODES / 64);
        gemm_nt<64, 64, 4, 4, false><<<g1, 256, 0, stream>>>(
            frozen, weight, cb, nullptr, nullptr, nullptr, nullptr, NCODES, DIM, DIM);
        rowsumsq<<<NCODES / 4, 256, 0, stream>>>(cb, fcn2, NCODES);
        rowsumsq<<<R_ROWS / 4, 256, 0, stream>>>(x, fxn2, R_ROWS);
        dim3 g2(NCODES / 128, R_ROWS / 128);
        gemm_nt<128, 128, 8, 8, true><<<g2, 256, 0, stream>>>(
            x, cb, nullptr, fxn2, fcn2, fpV, fpI, R_ROWS, NCODES, DIM);
        argmin_combine<<<R_ROWS / 256, 256, 0, stream>>>(
            fpV, fpI, fidx, out + (size_t)R_ROWS * DIM, NCODES / 128);
        rotate_rows<<<R_ROWS / 4, 256, 0, stream>>>(x, cb, fidx, out, flp);
        loss_reduce<<<1, 256, 0, stream>>>(flp, out + ((size_t)R_ROWS * DIM + R_ROWS));
    }
}

// Round 14
// 195.934 us; speedup vs baseline: 2.2290x; 1.0744x over previous
//
#include <hip/hip_runtime.h>
#include <hip/hip_bf16.h>
#include <cstdint>

// SimVQ forward: b=8, n=1024 (R=8192 rows), dim=512, codes C=4096.
// Outputs flat f32: rotated [8192*512], indices-as-float [8192], loss [1].
//
// Round-14: r13 (PASSING, 210us) + tail cuts:
//   (a) refine: 4 independent code-chains per wave-iteration (serial depth
//       16->4); (s,c)-min is order-independent => identical idx bits.
//   (b) cast_f16 fused INTO rowsumsq keeping rowsumsq's exact lane mapping
//       (float4 @ lane, lane+64) => xn2/cn2 bit-identical to r6; casts are
//       the same values written as 2x8B stores. Saves 2 launches + 24MB read.
// Score kernel, margins, cb f32 GEMM, combine/rotate/loss: r13 bits.

#define R_ROWS 8192
#define DIM    512
#define NCODES 4096
#define BK     16
#define MARGIN      1.5e-2f
#define TILE_MARGIN 1.8e-2f

typedef __attribute__((ext_vector_type(8))) _Float16 f16x8;
typedef __attribute__((ext_vector_type(4))) float f32x4;
typedef __attribute__((ext_vector_type(8))) unsigned short ushort8;

__device__ __forceinline__ void gload_lds16(const void* g, void* l) {
    __builtin_amdgcn_global_load_lds(
        (const __attribute__((address_space(1))) void*)g,
        (__attribute__((address_space(3))) void*)l, 16, 0, 0);
}

// ---------------- generic f32 NT GEMM (cb + fallback) -----------------------
template<int BM, int BN, int TM, int TN, bool ARGMIN>
__launch_bounds__(256)
__global__ void gemm_nt(const float* __restrict__ A, const float* __restrict__ Bm,
                        float* __restrict__ Cout,
                        const float* __restrict__ rowAdd, const float* __restrict__ colAdd,
                        float* __restrict__ pVal, int* __restrict__ pIdx,
                        int M, int N, int K) {
    constexpr int THREADS = (BM / TM) * (BN / TN);
    constexpr int PAD = 4;
    __shared__ float As[BK][BM + PAD];
    __shared__ float Bs[BK][BN + PAD];

    const int tid = threadIdx.x;
    const int tx = tid % (BN / TN);
    const int ty = tid / (BN / TN);
    const int rowBase = blockIdx.y * BM;
    const int colBase = blockIdx.x * BN;

    float acc[TM][TN];
#pragma unroll
    for (int i = 0; i < TM; i++)
#pragma unroll
        for (int j = 0; j < TN; j++) acc[i][j] = 0.f;

    constexpr int A_F4 = BM * BK / 4;
    constexpr int B_F4 = BN * BK / 4;
    const int nK = K / BK;

    for (int kt = 0; kt < nK; ++kt) {
        const int k0 = kt * BK;
#pragma unroll
        for (int f = 0; f < A_F4 / THREADS; ++f) {
            int e = tid + f * THREADS;
            int row = e >> 2;
            int kq = e & 3;
            float4 v = *reinterpret_cast<const float4*>(
                &A[(size_t)(rowBase + row) * K + k0 + kq * 4]);
            As[kq * 4 + 0][row] = v.x; As[kq * 4 + 1][row] = v.y;
            As[kq * 4 + 2][row] = v.z; As[kq * 4 + 3][row] = v.w;
        }
#pragma unroll
        for (int f = 0; f < B_F4 / THREADS; ++f) {
            int e = tid + f * THREADS;
            int row = e >> 2;
            int kq = e & 3;
            float4 v = *reinterpret_cast<const float4*>(
                &Bm[(size_t)(colBase + row) * K + k0 + kq * 4]);
            Bs[kq * 4 + 0][row] = v.x; Bs[kq * 4 + 1][row] = v.y;
            Bs[kq * 4 + 2][row] = v.z; Bs[kq * 4 + 3][row] = v.w;
        }
        __syncthreads();

#pragma unroll
        for (int k = 0; k < BK; k++) {
            float a[TM], b[TN];
#pragma unroll
            for (int i4 = 0; i4 < TM / 4; i4++) {
                float4 v = *reinterpret_cast<const float4*>(&As[k][ty * TM + i4 * 4]);
                a[i4 * 4 + 0] = v.x; a[i4 * 4 + 1] = v.y;
                a[i4 * 4 + 2] = v.z; a[i4 * 4 + 3] = v.w;
            }
#pragma unroll
            for (int j4 = 0; j4 < TN / 4; j4++) {
                float4 v = *reinterpret_cast<const float4*>(&Bs[k][tx * TN + j4 * 4]);
                b[j4 * 4 + 0] = v.x; b[j4 * 4 + 1] = v.y;
                b[j4 * 4 + 2] = v.z; b[j4 * 4 + 3] = v.w;
            }
#pragma unroll
            for (int i = 0; i < TM; i++)
#pragma unroll
                for (int j = 0; j < TN; j++) acc[i][j] = fmaf(a[i], b[j], acc[i][j]);
        }
        __syncthreads();
    }

    if constexpr (!ARGMIN) {
#pragma unroll
        for (int i = 0; i < TM; i++) {
#pragma unroll
            for (int j4 = 0; j4 < TN / 4; j4++) {
                float4 v = make_float4(acc[i][j4 * 4 + 0], acc[i][j4 * 4 + 1],
                                       acc[i][j4 * 4 + 2], acc[i][j4 * 4 + 3]);
                *reinterpret_cast<float4*>(
                    &Cout[(size_t)(rowBase + ty * TM + i) * N + colBase + tx * TN + j4 * 4]) = v;
            }
        }
    } else {
        constexpr int TX = BN / TN;
        __shared__ float rV[BM][TX + 1];
        __shared__ int   rI[BM][TX + 1];
        float xn[TM];
#pragma unroll
        for (int i = 0; i < TM; i++) xn[i] = rowAdd[rowBase + ty * TM + i];
        float cn[TN];
#pragma unroll
        for (int j = 0; j < TN; j++) cn[j] = colAdd[colBase + tx * TN + j];

#pragma unroll
        for (int i = 0; i < TM; i++) {
            float bv = 3.402823466e38f; int bi = 0;
#pragma unroll
            for (int j = 0; j < TN; j++) {
                float s = xn[i] + cn[j] - 2.f * acc[i][j];
                if (s < bv) { bv = s; bi = colBase + tx * TN + j; }
            }
            rV[ty * TM + i][tx] = bv;
            rI[ty * TM + i][tx] = bi;
        }
        __syncthreads();
        if (tid < BM) {
            float bv = 3.402823466e38f; int bi = 0;
#pragma unroll
            for (int t = 0; t < TX; t++) {
                float v = rV[tid][t];
                if (v < bv) { bv = v; bi = rI[tid][t]; }
            }
            int gr = rowBase + tid;
            pVal[(size_t)gr * gridDim.x + blockIdx.x] = bv;
            pIdx[(size_t)gr * gridDim.x + blockIdx.x] = bi;
        }
    }
}

// ------ per-row sum of squares (r6 lane mapping) + fused f16 cast -----------
// Lane mapping and summation order identical to r6 rowsumsq => same sum bits.
// The cast writes the SAME elements the lane loaded (4 @ lane*4, 4 @ 256+lane*4).
__global__ void rowsumsq_cast(const float* __restrict__ src, float* __restrict__ dst,
                              ushort* __restrict__ h16, int nRows) {
    int gw = (blockIdx.x * blockDim.x + threadIdx.x) >> 6;
    int lane = threadIdx.x & 63;
    if (gw >= nRows) return;
    const float4* s4 = reinterpret_cast<const float4*>(src + (size_t)gw * DIM);
    float4 a = s4[lane];
    float4 b = s4[lane + 64];
    float s = a.x * a.x + a.y * a.y + a.z * a.z + a.w * a.w
            + b.x * b.x + b.y * b.y + b.z * b.z + b.w * b.w;

    ushort ha[4], hb[4];
    {
        _Float16 t0 = (_Float16)a.x, t1 = (_Float16)a.y,
                 t2 = (_Float16)a.z, t3 = (_Float16)a.w;
        ha[0] = *reinterpret_cast<unsigned short*>(&t0);
        ha[1] = *reinterpret_cast<unsigned short*>(&t1);
        ha[2] = *reinterpret_cast<unsigned short*>(&t2);
        ha[3] = *reinterpret_cast<unsigned short*>(&t3);
        _Float16 u0 = (_Float16)b.x, u1 = (_Float16)b.y,
                 u2 = (_Float16)b.z, u3 = (_Float16)b.w;
        hb[0] = *reinterpret_cast<unsigned short*>(&u0);
        hb[1] = *reinterpret_cast<unsigned short*>(&u1);
        hb[2] = *reinterpret_cast<unsigned short*>(&u2);
        hb[3] = *reinterpret_cast<unsigned short*>(&u3);
    }
    ushort* rowp = h16 + (size_t)gw * DIM;
    *reinterpret_cast<uint2*>(rowp + lane * 4)       = *reinterpret_cast<uint2*>(ha);
    *reinterpret_cast<uint2*>(rowp + 256 + lane * 4) = *reinterpret_cast<uint2*>(hb);

#pragma unroll
    for (int o = 32; o; o >>= 1) s += __shfl_xor(s, o);
    if (lane == 0) dst[gw] = s;
}

// ------------- per-row sum of squares (fallback path only) ------------------
__global__ void rowsumsq(const float* __restrict__ src, float* __restrict__ dst, int nRows) {
    int gw = (blockIdx.x * blockDim.x + threadIdx.x) >> 6;
    int lane = threadIdx.x & 63;
    if (gw >= nRows) return;
    const float4* s4 = reinterpret_cast<const float4*>(src + (size_t)gw * DIM);
    float4 a = s4[lane];
    float4 b = s4[lane + 64];
    float s = a.x * a.x + a.y * a.y + a.z * a.z + a.w * a.w
            + b.x * b.x + b.y * b.y + b.z * b.z + b.w * b.w;
#pragma unroll
    for (int o = 32; o; o >>= 1) s += __shfl_xor(s, o);
    if (lane == 0) dst[gw] = s;
}

// ========= 128x128 MFMA f16 score GEMM, 4 waves, 16KB LDS (r13 bits) ========
__device__ __forceinline__ f16x8 read_frag(const char* half_base, int row, int g) {
    int gp = g ^ ((row >> 1) & 3);
    return *reinterpret_cast<const f16x8*>(half_base + row * 64 + gp * 16);
}

__device__ __forceinline__ void stage128(const ushort* __restrict__ src, int rowBase,
                                         int segElem, char* ldsBase, int tid) {
#pragma unroll
    for (int i = 0; i < 2; ++i) {
        int o = i * 4096 + tid * 16;
        int row = o >> 6;
        int gp  = (o >> 4) & 3;
        int g   = gp ^ ((row >> 1) & 3);
        const char* gsrc = (const char*)src + (size_t)(rowBase + row) * 1024
                         + (size_t)segElem * 2 + g * 16;
        gload_lds16(gsrc, ldsBase + i * 4096 + (tid >> 6) * 1024);
    }
}

__launch_bounds__(256)
__global__ void score_mfma4(const ushort* __restrict__ xh, const ushort* __restrict__ ch,
                            const float* __restrict__ xn2, const float* __restrict__ cn2,
                            float* __restrict__ pV1, float* __restrict__ pV2,
                            int* __restrict__ pI1) {
    __shared__ __align__(16) ushort As[4096];
    __shared__ __align__(16) ushort Bs[4096];

    int bid = blockIdx.x;
    int swz = (bid & 7) * 256 + (bid >> 3);
    int tileN = swz & 31;
    int tileM = swz >> 5;
    int rowBase = tileM * 128, colBase = tileN * 128;

    int tid = threadIdx.x, lane = tid & 63, w = tid >> 6;
    int wr = w >> 1, wc = w & 1;
    int g = lane >> 4, c15 = lane & 15;

    f32x4 acc[4][4];
#pragma unroll
    for (int m = 0; m < 4; m++)
#pragma unroll
        for (int n = 0; n < 4; n++) acc[m][n] = (f32x4){0.f, 0.f, 0.f, 0.f};

    for (int kk = 0; kk < 16; ++kk) {
        int se = kk * 32;
        stage128(xh, rowBase, se, (char*)As, tid);
        stage128(ch, colBase, se, (char*)Bs, tid);
        __syncthreads();

        f16x8 af[4], bf[4];
#pragma unroll
        for (int m = 0; m < 4; ++m)
            af[m] = read_frag((const char*)As, wr * 64 + m * 16 + c15, g);
#pragma unroll
        for (int n = 0; n < 4; ++n)
            bf[n] = read_frag((const char*)Bs, wc * 64 + n * 16 + c15, g);
#pragma unroll
        for (int m = 0; m < 4; ++m)
#pragma unroll
            for (int n = 0; n < 4; ++n)
                acc[m][n] = __builtin_amdgcn_mfma_f32_16x16x32_f16(
                    af[m], bf[n], acc[m][n], 0, 0, 0);
        __syncthreads();
    }

    float cnv[4];
#pragma unroll
    for (int n = 0; n < 4; ++n) cnv[n] = cn2[colBase + wc * 64 + n * 16 + c15];

    size_t gbase = (size_t)(tileN * 2 + wc) * R_ROWS + rowBase;
#pragma unroll
    for (int m = 0; m < 4; ++m) {
#pragma unroll
        for (int j = 0; j < 4; ++j) {
            int rl = wr * 64 + m * 16 + g * 4 + j;
            float xn = xn2[rowBase + rl];
            float v1 = 3.402823466e38f, v2 = 3.402823466e38f; int i1 = 0x7fffffff;
#pragma unroll
            for (int n = 0; n < 4; ++n) {
                float s = xn + cnv[n] - 2.f * acc[m][n][j];
                int ci = colBase + wc * 64 + n * 16 + c15;
                if (s < v1 || (s == v1 && ci < i1)) { v2 = v1; v1 = s; i1 = ci; }
                else if (s < v2) v2 = s;
            }
#pragma unroll
            for (int off = 1; off < 16; off <<= 1) {
                float ov1 = __shfl_xor(v1, off);
                int   oi1 = __shfl_xor(i1, off);
                float ov2 = __shfl_xor(v2, off);
                if (ov1 < v1 || (ov1 == v1 && oi1 < i1)) {
                    v2 = fminf(v1, ov2); v1 = ov1; i1 = oi1;
                } else {
                    v2 = fminf(v2, ov1);
                }
            }
            if (c15 == 0) {
                size_t o = gbase + rl;
                pV1[o] = v1; pV2[o] = v2; pI1[o] = i1;
            }
        }
    }
}

// ------------- combine per-group partials -> idx + near-tie flag ------------
__global__ void combine_flag(const float* __restrict__ pV1, const float* __restrict__ pV2,
                             const int* __restrict__ pI1,
                             int* __restrict__ idx, float* __restrict__ idxF,
                             int* __restrict__ flag, float* __restrict__ vminOut) {
    int r = blockIdx.x * blockDim.x + threadIdx.x;
    if (r >= R_ROWS) return;
    float v1 = 3.402823466e38f, v2 = 3.402823466e38f; int i1 = 0x7fffffff;
    for (int t = 0; t < 64; ++t) {
        float a1 = pV1[(size_t)t * R_ROWS + r];
        float a2 = pV2[(size_t)t * R_ROWS + r];
        int   ai = pI1[(size_t)t * R_ROWS + r];
        if (a1 < v1 || (a1 == v1 && ai < i1)) { v2 = fminf(v1, a2); v1 = a1; i1 = ai; }
        else { v2 = fminf(v2, a1); }
    }
    idx[r] = i1;
    idxF[r] = (float)i1;
    vminOut[r] = v1;
    flag[r] = (v2 - v1 < MARGIN) ? 1 : 0;
}

// ------------- exact f32 re-score, group-filtered, 4-way ILP ----------------
// Per wave-iteration: 4 independent code dot-chains (serial depth 16 -> 4).
// (s,c)-min over a set is order-independent; per-code math unchanged.
__launch_bounds__(256)
__global__ void refine_rows(const float* __restrict__ x, const float* __restrict__ cb,
                            const float* __restrict__ xn2, const float* __restrict__ cn2,
                            const float* __restrict__ pV1, const float* __restrict__ vmin,
                            const int* __restrict__ flag,
                            int* __restrict__ idx, float* __restrict__ idxF) {
    int r = blockIdx.x;
    if (flag[r] == 0) return;

    __shared__ float xs[DIM];
    __shared__ float wv[4];
    __shared__ int   wi[4];
    __shared__ unsigned long long maskS;
    int tid = threadIdx.x, lane = tid & 63, w = tid >> 6;

    for (int i = tid; i < DIM; i += 256) xs[i] = x[(size_t)r * DIM + i];

    float thr = vmin[r] + TILE_MARGIN;
    if (tid < 64) {   // wave 0 exactly
        float gm = pV1[(size_t)tid * R_ROWS + r];
        unsigned long long b = __ballot(gm <= thr);
        if (tid == 0) maskS = b;
    }
    __syncthreads();

    float x0 = xs[lane * 4 + 0], x1 = xs[lane * 4 + 1];
    float x2 = xs[lane * 4 + 2], x3 = xs[lane * 4 + 3];
    float y0 = xs[256 + lane * 4 + 0], y1 = xs[256 + lane * 4 + 1];
    float y2 = xs[256 + lane * 4 + 2], y3 = xs[256 + lane * 4 + 3];

    float xn = xn2[r];
    float v1 = 3.402823466e38f; int i1 = 0x7fffffff;

    unsigned long long mask = maskS;
    while (mask) {
        int gq = __ffsll((long long)mask) - 1;
        mask &= mask - 1;
#pragma unroll
        for (int t = 0; t < 4; ++t) {
            int c0 = gq * 64 + w * 4 + t * 16;   // 4 consecutive codes / wave
            const float4* cr0 = reinterpret_cast<const float4*>(cb + (size_t)(c0 + 0) * DIM);
            const float4* cr1 = reinterpret_cast<const float4*>(cb + (size_t)(c0 + 1) * DIM);
            const float4* cr2 = reinterpret_cast<const float4*>(cb + (size_t)(c0 + 2) * DIM);
            const float4* cr3 = reinterpret_cast<const float4*>(cb + (size_t)(c0 + 3) * DIM);
            float4 a0 = cr0[lane], b0 = cr0[lane + 64];
            float4 a1 = cr1[lane], b1 = cr1[lane + 64];
            float4 a2 = cr2[lane], b2 = cr2[lane + 64];
            float4 a3 = cr3[lane], b3 = cr3[lane + 64];
            float d0 = fmaf(x0, a0.x, fmaf(x1, a0.y, fmaf(x2, a0.z, fmaf(x3, a0.w,
                       fmaf(y0, b0.x, fmaf(y1, b0.y, fmaf(y2, b0.z, y3 * b0.w)))))));
            float d1 = fmaf(x0, a1.x, fmaf(x1, a1.y, fmaf(x2, a1.z, fmaf(x3, a1.w,
                       fmaf(y0, b1.x, fmaf(y1, b1.y, fmaf(y2, b1.z, y3 * b1.w)))))));
            float d2 = fmaf(x0, a2.x, fmaf(x1, a2.y, fmaf(x2, a2.z, fmaf(x3, a2.w,
                       fmaf(y0, b2.x, fmaf(y1, b2.y, fmaf(y2, b2.z, y3 * b2.w)))))));
            float d3 = fmaf(x0, a3.x, fmaf(x1, a3.y, fmaf(x2, a3.z, fmaf(x3, a3.w,
                       fmaf(y0, b3.x, fmaf(y1, b3.y, fmaf(y2, b3.z, y3 * b3.w)))))));
#pragma unroll
            for (int o = 32; o; o >>= 1) {
                d0 += __shfl_xor(d0, o);
                d1 += __shfl_xor(d1, o);
                d2 += __shfl_xor(d2, o);
                d3 += __shfl_xor(d3, o);
            }
            float s0 = xn + cn2[c0 + 0] - 2.f * d0;
            float s1 = xn + cn2[c0 + 1] - 2.f * d1;
            float s2 = xn + cn2[c0 + 2] - 2.f * d2;
            float s3 = xn + cn2[c0 + 3] - 2.f * d3;
            if (s0 < v1 || (s0 == v1 && (c0 + 0) < i1)) { v1 = s0; i1 = c0 + 0; }
            if (s1 < v1 || (s1 == v1 && (c0 + 1) < i1)) { v1 = s1; i1 = c0 + 1; }
            if (s2 < v1 || (s2 == v1 && (c0 + 2) < i1)) { v1 = s2; i1 = c0 + 2; }
            if (s3 < v1 || (s3 == v1 && (c0 + 3) < i1)) { v1 = s3; i1 = c0 + 3; }
        }
    }
    if (lane == 0) { wv[w] = v1; wi[w] = i1; }
    __syncthreads();
    if (tid == 0) {
        float bv = wv[0]; int bi = wi[0];
#pragma unroll
        for (int k = 1; k < 4; ++k) {
            if (wv[k] < bv || (wv[k] == bv && wi[k] < bi)) { bv = wv[k]; bi = wi[k]; }
        }
        idx[r] = bi; idxF[r] = (float)bi;
    }
}

// ------------- combine per-tile argmin partials (fallback path) -------------
__global__ void argmin_combine(const float* __restrict__ pVal, const int* __restrict__ pIdx,
                               int* __restrict__ idxOut, float* __restrict__ idxFloatOut,
                               int nTiles) {
    int r = blockIdx.x * blockDim.x + threadIdx.x;
    if (r >= R_ROWS) return;
    float bv = 3.402823466e38f; int bi = 0;
    for (int t = 0; t < nTiles; t++) {
        float v = pVal[(size_t)r * nTiles + t];
        if (v < bv) { bv = v; bi = pIdx[(size_t)r * nTiles + t]; }
    }
    idxOut[r] = bi;
    idxFloatOut[r] = (float)bi;
}

// ------------- rotation trick, one wave per row -----------------------------
__global__ void rotate_rows(const float* __restrict__ x, const float* __restrict__ cb,
                            const int* __restrict__ idx, float* __restrict__ out,
                            float* __restrict__ lossPartial) {
    int gw = (blockIdx.x * blockDim.x + threadIdx.x) >> 6;
    int lane = threadIdx.x & 63;
    if (gw >= R_ROWS) return;

    const float4* x4 = reinterpret_cast<const float4*>(x + (size_t)gw * DIM);
    float4 xa = x4[lane], xb = x4[lane + 64];
    int ci = idx[gw];
    const float4* q4 = reinterpret_cast<const float4*>(cb + (size_t)ci * DIM);
    float4 qa = q4[lane], qb = q4[lane + 64];

    float xe[8] = {xa.x, xa.y, xa.z, xa.w, xb.x, xb.y, xb.z, xb.w};
    float qe[8] = {qa.x, qa.y, qa.z, qa.w, qb.x, qb.y, qb.z, qb.w};

    auto wsum = [&](float v) {
#pragma unroll
        for (int o = 32; o; o >>= 1) v += __shfl_xor(v, o);
        return v;
    };

    float lx = 0.f, lq = 0.f, ld = 0.f;
#pragma unroll
    for (int e = 0; e < 8; e++) {
        lx += xe[e] * xe[e];
        lq += qe[e] * qe[e];
        float d = xe[e] - qe[e];
        ld += d * d;
    }
    float sx2 = wsum(lx);
    float sq2 = wsum(lq);
    float lp  = wsum(ld);

    float nx = sqrtf(sx2), nq = sqrtf(sq2);
    float inx = 1.f / fmaxf(nx, 1e-6f);
    float inq = 1.f / fmaxf(nq, 1e-6f);

    float ue[8], qh[8], we[8];
    float lw = 0.f;
#pragma unroll
    for (int e = 0; e < 8; e++) {
        ue[e] = xe[e] * inx;
        qh[e] = qe[e] * inq;
        we[e] = ue[e] + qh[e];
        lw += we[e] * we[e];
    }
    float sw2 = wsum(lw);
    float inw = 1.f / fmaxf(sqrtf(sw2), 1e-6f);

    float lew = 0.f, leu = 0.f;
#pragma unroll
    for (int e = 0; e < 8; e++) {
        we[e] *= inw;
        lew += xe[e] * we[e];
        leu += xe[e] * ue[e];
    }
    float ew = wsum(lew);
    float eu = wsum(leu);

    float scale = nq / fmaxf(nx, 1e-6f);
    float oe[8];
#pragma unroll
    for (int e = 0; e < 8; e++)
        oe[e] = (xe[e] - 2.f * ew * we[e] + 2.f * eu * qh[e]) * scale;

    float4* o4 = reinterpret_cast<float4*>(out + (size_t)gw * DIM);
    o4[lane]      = make_float4(oe[0], oe[1], oe[2], oe[3]);
    o4[lane + 64] = make_float4(oe[4], oe[5], oe[6], oe[7]);

    if (lane == 0) lossPartial[gw] = lp;
}

// ------------- final loss reduction -----------------------------------------
__global__ void loss_reduce(const float* __restrict__ lp, float* __restrict__ outScalar) {
    __shared__ float red[256];
    float s = 0.f;
    for (int i = threadIdx.x; i < R_ROWS; i += 256) s += lp[i];
    red[threadIdx.x] = s;
    __syncthreads();
    for (int o = 128; o; o >>= 1) {
        if (threadIdx.x < o) red[threadIdx.x] += red[threadIdx.x + o];
        __syncthreads();
    }
    if (threadIdx.x == 0)
        outScalar[0] = 1.25f * red[0] / (float)(R_ROWS * DIM);
}

extern "C" void kernel_launch(void* const* d_in, const int* in_sizes, int n_in,
                              void* d_out, int out_size, void* d_ws, size_t ws_size,
                              hipStream_t stream) {
    const float* x      = (const float*)d_in[0];   // [8192, 512]
    const float* frozen = (const float*)d_in[1];   // [4096, 512]
    const float* weight = (const float*)d_in[2];   // [512, 512]
    float* out = (float*)d_out;

    // ---- workspace layout (MFMA path), ~29 MB ----
    char* p = (char*)d_ws;
    float* cb  = (float*)p;            p += (size_t)NCODES * DIM * 4;
    ushort* xh = (ushort*)p;           p += (size_t)R_ROWS * DIM * 2;
    ushort* ch = (ushort*)p;           p += (size_t)NCODES * DIM * 2;
    float* cn2 = (float*)p;            p += NCODES * 4;
    float* xn2 = (float*)p;            p += R_ROWS * 4;
    float* pV1 = (float*)p;            p += (size_t)R_ROWS * 64 * 4;   // [64][8192]
    float* pV2 = (float*)p;            p += (size_t)R_ROWS * 64 * 4;
    int*   pI1 = (int*)p;              p += (size_t)R_ROWS * 64 * 4;
    int*   idx = (int*)p;              p += R_ROWS * 4;
    int*   flg = (int*)p;              p += R_ROWS * 4;
    float* vmn = (float*)p;            p += R_ROWS * 4;
    float* lp  = (float*)p;            p += R_ROWS * 4;
    size_t need = (size_t)(p - (char*)d_ws);

    if (ws_size >= need) {
        // 1. codebook = frozen @ W^T : f32 GEMM (round-6 bits)
        dim3 g1(DIM / 64, NCODES / 64);
        gemm_nt<64, 64, 4, 4, false><<<g1, 256, 0, stream>>>(
            frozen, weight, cb, nullptr, nullptr, nullptr, nullptr, NCODES, DIM, DIM);

        // 2. exact row norms (r6 bits) + fused f16 casts
        rowsumsq_cast<<<R_ROWS / 4, 256, 0, stream>>>(x, xn2, xh, R_ROWS);
        rowsumsq_cast<<<NCODES / 4, 256, 0, stream>>>(cb, cn2, ch, NCODES);

        // 3. 1-term f16 MFMA score GEMM (light blocks) + per-group partials
        score_mfma4<<<(R_ROWS / 128) * (NCODES / 128), 256, 0, stream>>>(
            xh, ch, xn2, cn2, pV1, pV2, pI1);

        // 4. combine + near-tie flag
        combine_flag<<<R_ROWS / 256, 256, 0, stream>>>(
            pV1, pV2, pI1, idx, out + (size_t)R_ROWS * DIM, flg, vmn);

        // 5. exact f32 re-score of flagged rows (group-filtered, 4-way ILP)
        refine_rows<<<R_ROWS, 256, 0, stream>>>(
            x, cb, xn2, cn2, pV1, vmn, flg, idx, out + (size_t)R_ROWS * DIM);

        // 6. rotation trick + loss
        rotate_rows<<<R_ROWS / 4, 256, 0, stream>>>(x, cb, idx, out, lp);
        loss_reduce<<<1, 256, 0, stream>>>(lp, out + ((size_t)R_ROWS * DIM + R_ROWS));
    } else {
        // fallback: proven f32 path (~11 MB)
        float* fcn2 = (float*)((char*)d_ws + (size_t)NCODES * DIM * 4);
        float* fxn2 = fcn2 + NCODES;
        float* fpV = fxn2 + R_ROWS;
        int*   fpI = (int*)(fpV + (size_t)R_ROWS * 32);
        int*   fidx = (int*)(fpI + (size_t)R_ROWS * 32);
        float* flp = (float*)(fidx + R_ROWS);
        dim3 g1(DIM / 64, NCODES / 64);
        gemm_nt<64, 64, 4, 4, false><<<g1, 256, 0, stream>>>(
            frozen, weight, cb, nullptr, nullptr, nullptr, nullptr, NCODES, DIM, DIM);
        rowsumsq<<<NCODES / 4, 256, 0, stream>>>(cb, fcn2, NCODES);
        rowsumsq<<<R_ROWS / 4, 256, 0, stream>>>(x, fxn2, R_ROWS);
        dim3 g2(NCODES / 128, R_ROWS / 128);
        gemm_nt<128, 128, 8, 8, true><<<g2, 256, 0, stream>>>(
            x, cb, nullptr, fxn2, fcn2, fpV, fpI, R_ROWS, NCODES, DIM);
        argmin_combine<<<R_ROWS / 256, 256, 0, stream>>>(
            fpV, fpI, fidx, out + (size_t)R_ROWS * DIM, NCODES / 128);
        rotate_rows<<<R_ROWS / 4, 256, 0, stream>>>(x, cb, fidx, out, flp);
        loss_reduce<<<1, 256, 0, stream>>>(flp, out + ((size_t)R_ROWS * DIM + R_ROWS));
    }
}

// Round 15
// 164.495 us; speedup vs baseline: 2.6550x; 1.1911x over previous
//
#include <hip/hip_runtime.h>
#include <hip/hip_bf16.h>
#include <cstdint>

// SimVQ forward: b=8, n=1024 (R=8192 rows), dim=512, codes C=4096.
// Outputs flat f32: rotated [8192*512], indices-as-float [8192], loss [1].
//
// Round-15: r14 (PASSING, 196us) + fused tail:
//   finalize_rows = combine_flag + refine + rotate + loss-partial in ONE
//   kernel (8192 blocks). Wave-0 butterfly top-2 merge of the 64 group
//   partials (top-2 w/ index tie-break is a total order => bit-identical
//   (v1,v2,i1) to the serial fold); flagged rows refine in-block (r14 4-way
//   ILP); rotate uses the LDS-staged x row (same bits) + in-register idx.
//   Saves 2 launches + idx/flg/vmn round-trips + one 16MB x re-read.
// Score kernel, margins, cb f32 GEMM, rowsumsq_cast: r14 bits.

#define R_ROWS 8192
#define DIM    512
#define NCODES 4096
#define BK     16
#define MARGIN      1.5e-2f
#define TILE_MARGIN 1.8e-2f

typedef __attribute__((ext_vector_type(8))) _Float16 f16x8;
typedef __attribute__((ext_vector_type(4))) float f32x4;
typedef __attribute__((ext_vector_type(8))) unsigned short ushort8;

__device__ __forceinline__ void gload_lds16(const void* g, void* l) {
    __builtin_amdgcn_global_load_lds(
        (const __attribute__((address_space(1))) void*)g,
        (__attribute__((address_space(3))) void*)l, 16, 0, 0);
}

// ---------------- generic f32 NT GEMM (cb + fallback) -----------------------
template<int BM, int BN, int TM, int TN, bool ARGMIN>
__launch_bounds__(256)
__global__ void gemm_nt(const float* __restrict__ A, const float* __restrict__ Bm,
                        float* __restrict__ Cout,
                        const float* __restrict__ rowAdd, const float* __restrict__ colAdd,
                        float* __restrict__ pVal, int* __restrict__ pIdx,
                        int M, int N, int K) {
    constexpr int THREADS = (BM / TM) * (BN / TN);
    constexpr int PAD = 4;
    __shared__ float As[BK][BM + PAD];
    __shared__ float Bs[BK][BN + PAD];

    const int tid = threadIdx.x;
    const int tx = tid % (BN / TN);
    const int ty = tid / (BN / TN);
    const int rowBase = blockIdx.y * BM;
    const int colBase = blockIdx.x * BN;

    float acc[TM][TN];
#pragma unroll
    for (int i = 0; i < TM; i++)
#pragma unroll
        for (int j = 0; j < TN; j++) acc[i][j] = 0.f;

    constexpr int A_F4 = BM * BK / 4;
    constexpr int B_F4 = BN * BK / 4;
    const int nK = K / BK;

    for (int kt = 0; kt < nK; ++kt) {
        const int k0 = kt * BK;
#pragma unroll
        for (int f = 0; f < A_F4 / THREADS; ++f) {
            int e = tid + f * THREADS;
            int row = e >> 2;
            int kq = e & 3;
            float4 v = *reinterpret_cast<const float4*>(
                &A[(size_t)(rowBase + row) * K + k0 + kq * 4]);
            As[kq * 4 + 0][row] = v.x; As[kq * 4 + 1][row] = v.y;
            As[kq * 4 + 2][row] = v.z; As[kq * 4 + 3][row] = v.w;
        }
#pragma unroll
        for (int f = 0; f < B_F4 / THREADS; ++f) {
            int e = tid + f * THREADS;
            int row = e >> 2;
            int kq = e & 3;
            float4 v = *reinterpret_cast<const float4*>(
                &Bm[(size_t)(colBase + row) * K + k0 + kq * 4]);
            Bs[kq * 4 + 0][row] = v.x; Bs[kq * 4 + 1][row] = v.y;
            Bs[kq * 4 + 2][row] = v.z; Bs[kq * 4 + 3][row] = v.w;
        }
        __syncthreads();

#pragma unroll
        for (int k = 0; k < BK; k++) {
            float a[TM], b[TN];
#pragma unroll
            for (int i4 = 0; i4 < TM / 4; i4++) {
                float4 v = *reinterpret_cast<const float4*>(&As[k][ty * TM + i4 * 4]);
                a[i4 * 4 + 0] = v.x; a[i4 * 4 + 1] = v.y;
                a[i4 * 4 + 2] = v.z; a[i4 * 4 + 3] = v.w;
            }
#pragma unroll
            for (int j4 = 0; j4 < TN / 4; j4++) {
                float4 v = *reinterpret_cast<const float4*>(&Bs[k][tx * TN + j4 * 4]);
                b[j4 * 4 + 0] = v.x; b[j4 * 4 + 1] = v.y;
                b[j4 * 4 + 2] = v.z; b[j4 * 4 + 3] = v.w;
            }
#pragma unroll
            for (int i = 0; i < TM; i++)
#pragma unroll
                for (int j = 0; j < TN; j++) acc[i][j] = fmaf(a[i], b[j], acc[i][j]);
        }
        __syncthreads();
    }

    if constexpr (!ARGMIN) {
#pragma unroll
        for (int i = 0; i < TM; i++) {
#pragma unroll
            for (int j4 = 0; j4 < TN / 4; j4++) {
                float4 v = make_float4(acc[i][j4 * 4 + 0], acc[i][j4 * 4 + 1],
                                       acc[i][j4 * 4 + 2], acc[i][j4 * 4 + 3]);
                *reinterpret_cast<float4*>(
                    &Cout[(size_t)(rowBase + ty * TM + i) * N + colBase + tx * TN + j4 * 4]) = v;
            }
        }
    } else {
        constexpr int TX = BN / TN;
        __shared__ float rV[BM][TX + 1];
        __shared__ int   rI[BM][TX + 1];
        float xn[TM];
#pragma unroll
        for (int i = 0; i < TM; i++) xn[i] = rowAdd[rowBase + ty * TM + i];
        float cn[TN];
#pragma unroll
        for (int j = 0; j < TN; j++) cn[j] = colAdd[colBase + tx * TN + j];

#pragma unroll
        for (int i = 0; i < TM; i++) {
            float bv = 3.402823466e38f; int bi = 0;
#pragma unroll
            for (int j = 0; j < TN; j++) {
                float s = xn[i] + cn[j] - 2.f * acc[i][j];
                if (s < bv) { bv = s; bi = colBase + tx * TN + j; }
            }
            rV[ty * TM + i][tx] = bv;
            rI[ty * TM + i][tx] = bi;
        }
        __syncthreads();
        if (tid < BM) {
            float bv = 3.402823466e38f; int bi = 0;
#pragma unroll
            for (int t = 0; t < TX; t++) {
                float v = rV[tid][t];
                if (v < bv) { bv = v; bi = rI[tid][t]; }
            }
            int gr = rowBase + tid;
            pVal[(size_t)gr * gridDim.x + blockIdx.x] = bv;
            pIdx[(size_t)gr * gridDim.x + blockIdx.x] = bi;
        }
    }
}

// ------ per-row sum of squares (r6 lane mapping) + fused f16 cast -----------
__global__ void rowsumsq_cast(const float* __restrict__ src, float* __restrict__ dst,
                              ushort* __restrict__ h16, int nRows) {
    int gw = (blockIdx.x * blockDim.x + threadIdx.x) >> 6;
    int lane = threadIdx.x & 63;
    if (gw >= nRows) return;
    const float4* s4 = reinterpret_cast<const float4*>(src + (size_t)gw * DIM);
    float4 a = s4[lane];
    float4 b = s4[lane + 64];
    float s = a.x * a.x + a.y * a.y + a.z * a.z + a.w * a.w
            + b.x * b.x + b.y * b.y + b.z * b.z + b.w * b.w;

    ushort ha[4], hb[4];
    {
        _Float16 t0 = (_Float16)a.x, t1 = (_Float16)a.y,
                 t2 = (_Float16)a.z, t3 = (_Float16)a.w;
        ha[0] = *reinterpret_cast<unsigned short*>(&t0);
        ha[1] = *reinterpret_cast<unsigned short*>(&t1);
        ha[2] = *reinterpret_cast<unsigned short*>(&t2);
        ha[3] = *reinterpret_cast<unsigned short*>(&t3);
        _Float16 u0 = (_Float16)b.x, u1 = (_Float16)b.y,
                 u2 = (_Float16)b.z, u3 = (_Float16)b.w;
        hb[0] = *reinterpret_cast<unsigned short*>(&u0);
        hb[1] = *reinterpret_cast<unsigned short*>(&u1);
        hb[2] = *reinterpret_cast<unsigned short*>(&u2);
        hb[3] = *reinterpret_cast<unsigned short*>(&u3);
    }
    ushort* rowp = h16 + (size_t)gw * DIM;
    *reinterpret_cast<uint2*>(rowp + lane * 4)       = *reinterpret_cast<uint2*>(ha);
    *reinterpret_cast<uint2*>(rowp + 256 + lane * 4) = *reinterpret_cast<uint2*>(hb);

#pragma unroll
    for (int o = 32; o; o >>= 1) s += __shfl_xor(s, o);
    if (lane == 0) dst[gw] = s;
}

// ------------- per-row sum of squares (fallback path only) ------------------
__global__ void rowsumsq(const float* __restrict__ src, float* __restrict__ dst, int nRows) {
    int gw = (blockIdx.x * blockDim.x + threadIdx.x) >> 6;
    int lane = threadIdx.x & 63;
    if (gw >= nRows) return;
    const float4* s4 = reinterpret_cast<const float4*>(src + (size_t)gw * DIM);
    float4 a = s4[lane];
    float4 b = s4[lane + 64];
    float s = a.x * a.x + a.y * a.y + a.z * a.z + a.w * a.w
            + b.x * b.x + b.y * b.y + b.z * b.z + b.w * b.w;
#pragma unroll
    for (int o = 32; o; o >>= 1) s += __shfl_xor(s, o);
    if (lane == 0) dst[gw] = s;
}

// ========= 128x128 MFMA f16 score GEMM, 4 waves, 16KB LDS (r13 bits) ========
__device__ __forceinline__ f16x8 read_frag(const char* half_base, int row, int g) {
    int gp = g ^ ((row >> 1) & 3);
    return *reinterpret_cast<const f16x8*>(half_base + row * 64 + gp * 16);
}

__device__ __forceinline__ void stage128(const ushort* __restrict__ src, int rowBase,
                                         int segElem, char* ldsBase, int tid) {
#pragma unroll
    for (int i = 0; i < 2; ++i) {
        int o = i * 4096 + tid * 16;
        int row = o >> 6;
        int gp  = (o >> 4) & 3;
        int g   = gp ^ ((row >> 1) & 3);
        const char* gsrc = (const char*)src + (size_t)(rowBase + row) * 1024
                         + (size_t)segElem * 2 + g * 16;
        gload_lds16(gsrc, ldsBase + i * 4096 + (tid >> 6) * 1024);
    }
}

__launch_bounds__(256)
__global__ void score_mfma4(const ushort* __restrict__ xh, const ushort* __restrict__ ch,
                            const float* __restrict__ xn2, const float* __restrict__ cn2,
                            float* __restrict__ pV1, float* __restrict__ pV2,
                            int* __restrict__ pI1) {
    __shared__ __align__(16) ushort As[4096];
    __shared__ __align__(16) ushort Bs[4096];

    int bid = blockIdx.x;
    int swz = (bid & 7) * 256 + (bid >> 3);
    int tileN = swz & 31;
    int tileM = swz >> 5;
    int rowBase = tileM * 128, colBase = tileN * 128;

    int tid = threadIdx.x, lane = tid & 63, w = tid >> 6;
    int wr = w >> 1, wc = w & 1;
    int g = lane >> 4, c15 = lane & 15;

    f32x4 acc[4][4];
#pragma unroll
    for (int m = 0; m < 4; m++)
#pragma unroll
        for (int n = 0; n < 4; n++) acc[m][n] = (f32x4){0.f, 0.f, 0.f, 0.f};

    for (int kk = 0; kk < 16; ++kk) {
        int se = kk * 32;
        stage128(xh, rowBase, se, (char*)As, tid);
        stage128(ch, colBase, se, (char*)Bs, tid);
        __syncthreads();

        f16x8 af[4], bf[4];
#pragma unroll
        for (int m = 0; m < 4; ++m)
            af[m] = read_frag((const char*)As, wr * 64 + m * 16 + c15, g);
#pragma unroll
        for (int n = 0; n < 4; ++n)
            bf[n] = read_frag((const char*)Bs, wc * 64 + n * 16 + c15, g);
#pragma unroll
        for (int m = 0; m < 4; ++m)
#pragma unroll
            for (int n = 0; n < 4; ++n)
                acc[m][n] = __builtin_amdgcn_mfma_f32_16x16x32_f16(
                    af[m], bf[n], acc[m][n], 0, 0, 0);
        __syncthreads();
    }

    float cnv[4];
#pragma unroll
    for (int n = 0; n < 4; ++n) cnv[n] = cn2[colBase + wc * 64 + n * 16 + c15];

    size_t gbase = (size_t)(tileN * 2 + wc) * R_ROWS + rowBase;
#pragma unroll
    for (int m = 0; m < 4; ++m) {
#pragma unroll
        for (int j = 0; j < 4; ++j) {
            int rl = wr * 64 + m * 16 + g * 4 + j;
            float xn = xn2[rowBase + rl];
            float v1 = 3.402823466e38f, v2 = 3.402823466e38f; int i1 = 0x7fffffff;
#pragma unroll
            for (int n = 0; n < 4; ++n) {
                float s = xn + cnv[n] - 2.f * acc[m][n][j];
                int ci = colBase + wc * 64 + n * 16 + c15;
                if (s < v1 || (s == v1 && ci < i1)) { v2 = v1; v1 = s; i1 = ci; }
                else if (s < v2) v2 = s;
            }
#pragma unroll
            for (int off = 1; off < 16; off <<= 1) {
                float ov1 = __shfl_xor(v1, off);
                int   oi1 = __shfl_xor(i1, off);
                float ov2 = __shfl_xor(v2, off);
                if (ov1 < v1 || (ov1 == v1 && oi1 < i1)) {
                    v2 = fminf(v1, ov2); v1 = ov1; i1 = oi1;
                } else {
                    v2 = fminf(v2, ov1);
                }
            }
            if (c15 == 0) {
                size_t o = gbase + rl;
                pV1[o] = v1; pV2[o] = v2; pI1[o] = i1;
            }
        }
    }
}

// ===== fused tail: combine (butterfly top-2) + refine + rotate + loss =======
__launch_bounds__(256)
__global__ void finalize_rows(const float* __restrict__ x, const float* __restrict__ cb,
                              const float* __restrict__ xn2, const float* __restrict__ cn2,
                              const float* __restrict__ pV1, const float* __restrict__ pV2,
                              const int* __restrict__ pI1,
                              float* __restrict__ out, float* __restrict__ idxF,
                              float* __restrict__ lossPartial) {
    int r = blockIdx.x;
    int tid = threadIdx.x, lane = tid & 63, w = tid >> 6;

    __shared__ float xs[DIM];
    __shared__ float wv[4];
    __shared__ int   wi[4];
    __shared__ unsigned long long maskS;
    __shared__ int   idxS, flagS;
    __shared__ float vminS;

    for (int i = tid; i < DIM; i += 256) xs[i] = x[(size_t)r * DIM + i];

    // ---- combine: wave 0, one group per lane, butterfly top-2 merge ----
    if (w == 0) {
        float a1 = pV1[(size_t)lane * R_ROWS + r];
        float a2 = pV2[(size_t)lane * R_ROWS + r];
        int   ai = pI1[(size_t)lane * R_ROWS + r];
        float v1 = a1, v2 = a2; int i1 = ai;
#pragma unroll
        for (int off = 1; off < 64; off <<= 1) {
            float o1 = __shfl_xor(v1, off);
            float o2 = __shfl_xor(v2, off);
            int   oi = __shfl_xor(i1, off);
            if (o1 < v1 || (o1 == v1 && oi < i1)) { v2 = fminf(o2, v1); v1 = o1; i1 = oi; }
            else { v2 = fminf(v2, o1); }
        }
        // group pass-mask vs merged vmin (all lanes hold merged v1 now)
        unsigned long long b = __ballot(a1 <= v1 + TILE_MARGIN);
        if (lane == 0) {
            maskS = b; idxS = i1; vminS = v1;
            flagS = (v2 - v1 < MARGIN) ? 1 : 0;
        }
    }
    __syncthreads();

    float x0 = xs[lane * 4 + 0], x1 = xs[lane * 4 + 1];
    float x2 = xs[lane * 4 + 2], x3 = xs[lane * 4 + 3];
    float y0 = xs[256 + lane * 4 + 0], y1 = xs[256 + lane * 4 + 1];
    float y2 = xs[256 + lane * 4 + 2], y3 = xs[256 + lane * 4 + 3];
    float xn = xn2[r];

    // ---- refine (flagged rows only): r14 4-way ILP ----
    if (flagS) {
        float v1 = 3.402823466e38f; int i1 = 0x7fffffff;
        unsigned long long mask = maskS;
        while (mask) {
            int gq = __ffsll((long long)mask) - 1;
            mask &= mask - 1;
#pragma unroll
            for (int t = 0; t < 4; ++t) {
                int c0 = gq * 64 + w * 4 + t * 16;
                const float4* cr0 = reinterpret_cast<const float4*>(cb + (size_t)(c0 + 0) * DIM);
                const float4* cr1 = reinterpret_cast<const float4*>(cb + (size_t)(c0 + 1) * DIM);
                const float4* cr2 = reinterpret_cast<const float4*>(cb + (size_t)(c0 + 2) * DIM);
                const float4* cr3 = reinterpret_cast<const float4*>(cb + (size_t)(c0 + 3) * DIM);
                float4 a0 = cr0[lane], b0 = cr0[lane + 64];
                float4 a1 = cr1[lane], b1 = cr1[lane + 64];
                float4 a2 = cr2[lane], b2 = cr2[lane + 64];
                float4 a3 = cr3[lane], b3 = cr3[lane + 64];
                float d0 = fmaf(x0, a0.x, fmaf(x1, a0.y, fmaf(x2, a0.z, fmaf(x3, a0.w,
                           fmaf(y0, b0.x, fmaf(y1, b0.y, fmaf(y2, b0.z, y3 * b0.w)))))));
                float d1 = fmaf(x0, a1.x, fmaf(x1, a1.y, fmaf(x2, a1.z, fmaf(x3, a1.w,
                           fmaf(y0, b1.x, fmaf(y1, b1.y, fmaf(y2, b1.z, y3 * b1.w)))))));
                float d2 = fmaf(x0, a2.x, fmaf(x1, a2.y, fmaf(x2, a2.z, fmaf(x3, a2.w,
                           fmaf(y0, b2.x, fmaf(y1, b2.y, fmaf(y2, b2.z, y3 * b2.w)))))));
                float d3 = fmaf(x0, a3.x, fmaf(x1, a3.y, fmaf(x2, a3.z, fmaf(x3, a3.w,
                           fmaf(y0, b3.x, fmaf(y1, b3.y, fmaf(y2, b3.z, y3 * b3.w)))))));
#pragma unroll
                for (int o = 32; o; o >>= 1) {
                    d0 += __shfl_xor(d0, o);
                    d1 += __shfl_xor(d1, o);
                    d2 += __shfl_xor(d2, o);
                    d3 += __shfl_xor(d3, o);
                }
                float s0 = xn + cn2[c0 + 0] - 2.f * d0;
                float s1 = xn + cn2[c0 + 1] - 2.f * d1;
                float s2 = xn + cn2[c0 + 2] - 2.f * d2;
                float s3 = xn + cn2[c0 + 3] - 2.f * d3;
                if (s0 < v1 || (s0 == v1 && (c0 + 0) < i1)) { v1 = s0; i1 = c0 + 0; }
                if (s1 < v1 || (s1 == v1 && (c0 + 1) < i1)) { v1 = s1; i1 = c0 + 1; }
                if (s2 < v1 || (s2 == v1 && (c0 + 2) < i1)) { v1 = s2; i1 = c0 + 2; }
                if (s3 < v1 || (s3 == v1 && (c0 + 3) < i1)) { v1 = s3; i1 = c0 + 3; }
            }
        }
        if (lane == 0) { wv[w] = v1; wi[w] = i1; }
        __syncthreads();
        if (tid == 0) {
            float bv = wv[0]; int bi = wi[0];
#pragma unroll
            for (int k = 1; k < 4; ++k) {
                if (wv[k] < bv || (wv[k] == bv && wi[k] < bi)) { bv = wv[k]; bi = wi[k]; }
            }
            idxS = bi;
        }
        __syncthreads();
    }

    // ---- rotate (wave 0; x-row bits from LDS == global bits) ----
    if (w == 0) {
        int ci = idxS;
        const float4* q4 = reinterpret_cast<const float4*>(cb + (size_t)ci * DIM);
        float4 qa = q4[lane], qb = q4[lane + 64];

        float xe[8] = {x0, x1, x2, x3, y0, y1, y2, y3};
        float qe[8] = {qa.x, qa.y, qa.z, qa.w, qb.x, qb.y, qb.z, qb.w};

        auto wsum = [&](float v) {
#pragma unroll
            for (int o = 32; o; o >>= 1) v += __shfl_xor(v, o);
            return v;
        };

        float lx = 0.f, lq = 0.f, ld = 0.f;
#pragma unroll
        for (int e = 0; e < 8; e++) {
            lx += xe[e] * xe[e];
            lq += qe[e] * qe[e];
            float d = xe[e] - qe[e];
            ld += d * d;
        }
        float sx2 = wsum(lx);
        float sq2 = wsum(lq);
        float lp  = wsum(ld);

        float nx = sqrtf(sx2), nq = sqrtf(sq2);
        float inx = 1.f / fmaxf(nx, 1e-6f);
        float inq = 1.f / fmaxf(nq, 1e-6f);

        float ue[8], qh[8], we[8];
        float lw = 0.f;
#pragma unroll
        for (int e = 0; e < 8; e++) {
            ue[e] = xe[e] * inx;
            qh[e] = qe[e] * inq;
            we[e] = ue[e] + qh[e];
            lw += we[e] * we[e];
        }
        float sw2 = wsum(lw);
        float inw = 1.f / fmaxf(sqrtf(sw2), 1e-6f);

        float lew = 0.f, leu = 0.f;
#pragma unroll
        for (int e = 0; e < 8; e++) {
            we[e] *= inw;
            lew += xe[e] * we[e];
            leu += xe[e] * ue[e];
        }
        float ew = wsum(lew);
        float eu = wsum(leu);

        float scale = nq / fmaxf(nx, 1e-6f);
        float oe[8];
#pragma unroll
        for (int e = 0; e < 8; e++)
            oe[e] = (xe[e] - 2.f * ew * we[e] + 2.f * eu * qh[e]) * scale;

        float4* o4 = reinterpret_cast<float4*>(out + (size_t)r * DIM);
        o4[lane]      = make_float4(oe[0], oe[1], oe[2], oe[3]);
        o4[lane + 64] = make_float4(oe[4], oe[5], oe[6], oe[7]);

        if (lane == 0) {
            lossPartial[r] = lp;
            idxF[r] = (float)idxS;
        }
    }
}

// ------------- combine per-tile argmin partials (fallback path) -------------
__global__ void argmin_combine(const float* __restrict__ pVal, const int* __restrict__ pIdx,
                               int* __restrict__ idxOut, float* __restrict__ idxFloatOut,
                               int nTiles) {
    int r = blockIdx.x * blockDim.x + threadIdx.x;
    if (r >= R_ROWS) return;
    float bv = 3.402823466e38f; int bi = 0;
    for (int t = 0; t < nTiles; t++) {
        float v = pVal[(size_t)r * nTiles + t];
        if (v < bv) { bv = v; bi = pIdx[(size_t)r * nTiles + t]; }
    }
    idxOut[r] = bi;
    idxFloatOut[r] = (float)bi;
}

// ------------- rotation trick, one wave per row (fallback path) -------------
__global__ void rotate_rows(const float* __restrict__ x, const float* __restrict__ cb,
                            const int* __restrict__ idx, float* __restrict__ out,
                            float* __restrict__ lossPartial) {
    int gw = (blockIdx.x * blockDim.x + threadIdx.x) >> 6;
    int lane = threadIdx.x & 63;
    if (gw >= R_ROWS) return;

    const float4* x4 = reinterpret_cast<const float4*>(x + (size_t)gw * DIM);
    float4 xa = x4[lane], xb = x4[lane + 64];
    int ci = idx[gw];
    const float4* q4 = reinterpret_cast<const float4*>(cb + (size_t)ci * DIM);
    float4 qa = q4[lane], qb = q4[lane + 64];

    float xe[8] = {xa.x, xa.y, xa.z, xa.w, xb.x, xb.y, xb.z, xb.w};
    float qe[8] = {qa.x, qa.y, qa.z, qa.w, qb.x, qb.y, qb.z, qb.w};

    auto wsum = [&](float v) {
#pragma unroll
        for (int o = 32; o; o >>= 1) v += __shfl_xor(v, o);
        return v;
    };

    float lx = 0.f, lq = 0.f, ld = 0.f;
#pragma unroll
    for (int e = 0; e < 8; e++) {
        lx += xe[e] * xe[e];
        lq += qe[e] * qe[e];
        float d = xe[e] - qe[e];
        ld += d * d;
    }
    float sx2 = wsum(lx);
    float sq2 = wsum(lq);
    float lp  = wsum(ld);

    float nx = sqrtf(sx2), nq = sqrtf(sq2);
    float inx = 1.f / fmaxf(nx, 1e-6f);
    float inq = 1.f / fmaxf(nq, 1e-6f);

    float ue[8], qh[8], we[8];
    float lw = 0.f;
#pragma unroll
    for (int e = 0; e < 8; e++) {
        ue[e] = xe[e] * inx;
        qh[e] = qe[e] * inq;
        we[e] = ue[e] + qh[e];
        lw += we[e] * we[e];
    }
    float sw2 = wsum(lw);
    float inw = 1.f / fmaxf(sqrtf(sw2), 1e-6f);

    float lew = 0.f, leu = 0.f;
#pragma unroll
    for (int e = 0; e < 8; e++) {
        we[e] *= inw;
        lew += xe[e] * we[e];
        leu += xe[e] * ue[e];
    }
    float ew = wsum(lew);
    float eu = wsum(leu);

    float scale = nq / fmaxf(nx, 1e-6f);
    float oe[8];
#pragma unroll
    for (int e = 0; e < 8; e++)
        oe[e] = (xe[e] - 2.f * ew * we[e] + 2.f * eu * qh[e]) * scale;

    float4* o4 = reinterpret_cast<float4*>(out + (size_t)gw * DIM);
    o4[lane]      = make_float4(oe[0], oe[1], oe[2], oe[3]);
    o4[lane + 64] = make_float4(oe[4], oe[5], oe[6], oe[7]);

    if (lane == 0) lossPartial[gw] = lp;
}

// ------------- final loss reduction -----------------------------------------
__global__ void loss_reduce(const float* __restrict__ lp, float* __restrict__ outScalar) {
    __shared__ float red[256];
    float s = 0.f;
    for (int i = threadIdx.x; i < R_ROWS; i += 256) s += lp[i];
    red[threadIdx.x] = s;
    __syncthreads();
    for (int o = 128; o; o >>= 1) {
        if (threadIdx.x < o) red[threadIdx.x] += red[threadIdx.x + o];
        __syncthreads();
    }
    if (threadIdx.x == 0)
        outScalar[0] = 1.25f * red[0] / (float)(R_ROWS * DIM);
}

extern "C" void kernel_launch(void* const* d_in, const int* in_sizes, int n_in,
                              void* d_out, int out_size, void* d_ws, size_t ws_size,
                              hipStream_t stream) {
    const float* x      = (const float*)d_in[0];   // [8192, 512]
    const float* frozen = (const float*)d_in[1];   // [4096, 512]
    const float* weight = (const float*)d_in[2];   // [512, 512]
    float* out = (float*)d_out;

    // ---- workspace layout (MFMA path), ~29 MB ----
    char* p = (char*)d_ws;
    float* cb  = (float*)p;            p += (size_t)NCODES * DIM * 4;
    ushort* xh = (ushort*)p;           p += (size_t)R_ROWS * DIM * 2;
    ushort* ch = (ushort*)p;           p += (size_t)NCODES * DIM * 2;
    float* cn2 = (float*)p;            p += NCODES * 4;
    float* xn2 = (float*)p;            p += R_ROWS * 4;
    float* pV1 = (float*)p;            p += (size_t)R_ROWS * 64 * 4;   // [64][8192]
    float* pV2 = (float*)p;            p += (size_t)R_ROWS * 64 * 4;
    int*   pI1 = (int*)p;              p += (size_t)R_ROWS * 64 * 4;
    int*   idx = (int*)p;              p += R_ROWS * 4;
    int*   flg = (int*)p;              p += R_ROWS * 4;
    float* vmn = (float*)p;            p += R_ROWS * 4;
    float* lp  = (float*)p;            p += R_ROWS * 4;
    size_t need = (size_t)(p - (char*)d_ws);

    if (ws_size >= need) {
        // 1. codebook = frozen @ W^T : f32 GEMM (round-6 bits)
        dim3 g1(DIM / 64, NCODES / 64);
        gemm_nt<64, 64, 4, 4, false><<<g1, 256, 0, stream>>>(
            frozen, weight, cb, nullptr, nullptr, nullptr, nullptr, NCODES, DIM, DIM);

        // 2. exact row norms (r6 bits) + fused f16 casts
        rowsumsq_cast<<<R_ROWS / 4, 256, 0, stream>>>(x, xn2, xh, R_ROWS);
        rowsumsq_cast<<<NCODES / 4, 256, 0, stream>>>(cb, cn2, ch, NCODES);

        // 3. 1-term f16 MFMA score GEMM (light blocks) + per-group partials
        score_mfma4<<<(R_ROWS / 128) * (NCODES / 128), 256, 0, stream>>>(
            xh, ch, xn2, cn2, pV1, pV2, pI1);

        // 4. fused tail: combine + refine + rotate + loss partials
        finalize_rows<<<R_ROWS, 256, 0, stream>>>(
            x, cb, xn2, cn2, pV1, pV2, pI1,
            out, out + (size_t)R_ROWS * DIM, lp);

        // 5. final loss scalar
        loss_reduce<<<1, 256, 0, stream>>>(lp, out + ((size_t)R_ROWS * DIM + R_ROWS));
    } else {
        // fallback: proven f32 path (~11 MB)
        float* fcn2 = (float*)((char*)d_ws + (size_t)NCODES * DIM * 4);
        float* fxn2 = fcn2 + NCODES;
        float* fpV = fxn2 + R_ROWS;
        int*   fpI = (int*)(fpV + (size_t)R_ROWS * 32);
        int*   fidx = (int*)(fpI + (size_t)R_ROWS * 32);
        float* flp = (float*)(fidx + R_ROWS);
        dim3 g1(DIM / 64, NCODES / 64);
        gemm_nt<64, 64, 4, 4, false><<<g1, 256, 0, stream>>>(
            frozen, weight, cb, nullptr, nullptr, nullptr, nullptr, NCODES, DIM, DIM);
        rowsumsq<<<NCODES / 4, 256, 0, stream>>>(cb, fcn2, NCODES);
        rowsumsq<<<R_ROWS / 4, 256, 0, stream>>>(x, fxn2, R_ROWS);
        dim3 g2(NCODES / 128, R_ROWS / 128);
        gemm_nt<128, 128, 8, 8, true><<<g2, 256, 0, stream>>>(
            x, cb, nullptr, fxn2, fcn2, fpV, fpI, R_ROWS, NCODES, DIM);
        argmin_combine<<<R_ROWS / 256, 256, 0, stream>>>(
            fpV, fpI, fidx, out + (size_t)R_ROWS * DIM, NCODES / 128);
        rotate_rows<<<R_ROWS / 4, 256, 0, stream>>>(x, cb, fidx, out, flp);
        loss_reduce<<<1, 256, 0, stream>>>(flp, out + ((size_t)R_ROWS * DIM + R_ROWS));
    }
}